// Round 9
// baseline (896.973 us; speedup 1.0000x reference)
//
#include <hip/hip_runtime.h>
#include <math.h>

#define NTOK 197
#define CD   768
#define NH   12
#define DH   64
#define NBATCH 64
#define RTOK 98
#define KTOK 99
#define THRN 1941   /* count(w >= thr) >= thr_idx+1 = 1941 */
#define WTOT (KTOK*RTOK)   /* 9702 */
#define SROWS 208

typedef __attribute__((ext_vector_type(8))) short short8;
typedef __attribute__((ext_vector_type(8))) unsigned short u16x8;
typedef __attribute__((ext_vector_type(4))) float floatx4;

__device__ __forceinline__ int clamp196(int v){ return ((unsigned)v > 196u) ? 196 : v; }
__device__ __forceinline__ unsigned short f2b(float f){
  unsigned u = __float_as_uint(f);
  return (unsigned short)((u + 0x7FFFu + ((u>>16)&1u)) >> 16);
}
__device__ __forceinline__ float us2f(unsigned short u){ return __uint_as_float(((unsigned)u)<<16); }
// LDS chunk swizzle for short[row][32] tiles: XOR 16B-chunk index with (row>>1)&3.
__device__ __forceinline__ int swz(int row, int q){ return q ^ (((row>>1)&3)<<3); }

// load up to 8 fp32 (rem valid), split into bf16 hi + bf16 lo
__device__ __forceinline__ void ldsplit(const float* ap, int rem, u16x8& h, u16x8& l){
  float v[8];
  if (rem >= 8) {
    float4 t0 = *(const float4*)ap, t1 = *(const float4*)(ap+4);
    v[0]=t0.x; v[1]=t0.y; v[2]=t0.z; v[3]=t0.w;
    v[4]=t1.x; v[5]=t1.y; v[6]=t1.z; v[7]=t1.w;
  } else {
#pragma unroll
    for (int j=0;j<8;j++) v[j] = (j < rem) ? ap[j] : 0.f;
  }
#pragma unroll
  for (int j=0;j<8;j++){
    unsigned short hh = f2b(v[j]);
    h[j] = hh;
    l[j] = f2b(v[j] - us2f(hh));
  }
}

// ---------------- diagnostic fill ----------------
__global__ __launch_bounds__(256) void fill_kernel(float* __restrict__ out, int n, float val)
{
  int i = blockIdx.x*256 + threadIdx.x;
  if (i < n) out[i] = val;
}

// ---------------- transpose+cast: dst[n][k] = bf16(src[k][col0+n]) ----------------
__global__ __launch_bounds__(256) void tcast_k(const float* __restrict__ src, int K, int ldn, int col0,
                                               unsigned short* __restrict__ dst)
{
  __shared__ float t[32][33];
  int n0 = blockIdx.x*32, k0 = blockIdx.y*32;
  int lx = threadIdx.x & 31, ly = threadIdx.x >> 5;
#pragma unroll
  for (int i=0;i<4;i++)
    t[ly + i*8][lx] = src[(long)(k0 + ly + i*8)*ldn + col0 + n0 + lx];
  __syncthreads();
#pragma unroll
  for (int i=0;i<4;i++){
    int n = ly + i*8;
    dst[(long)(n0 + n)*K + k0 + lx] = f2b(t[lx][n]);
  }
}

// ---------------- transpose + hi/lo split ----------------
__global__ __launch_bounds__(256) void tcast3_k(const float* __restrict__ src, int K, int ldn, int col0,
                                                unsigned short* __restrict__ dsth,
                                                unsigned short* __restrict__ dstl)
{
  __shared__ float t[32][33];
  int n0 = blockIdx.x*32, k0 = blockIdx.y*32;
  int lx = threadIdx.x & 31, ly = threadIdx.x >> 5;
#pragma unroll
  for (int i=0;i<4;i++)
    t[ly + i*8][lx] = src[(long)(k0 + ly + i*8)*ldn + col0 + n0 + lx];
  __syncthreads();
#pragma unroll
  for (int i=0;i<4;i++){
    int n = ly + i*8;
    float v = t[lx][n];
    unsigned short h = f2b(v);
    dsth[(long)(n0 + n)*K + k0 + lx] = h;
    dstl[(long)(n0 + n)*K + k0 + lx] = f2b(v - us2f(h));
  }
}

// ---------------- LayerNorm (row 768; bf16 hi (+ optional lo) out) ----------------
__global__ __launch_bounds__(256) void ln_kernel(const float* __restrict__ xin,
                                                 const float* __restrict__ gam,
                                                 const float* __restrict__ bet,
                                                 unsigned short* __restrict__ outh,
                                                 unsigned short* __restrict__ outl)
{
  int row = blockIdx.x;
  int tid = threadIdx.x;
  long base = (long)row * CD;
  float v[3];
#pragma unroll
  for (int i=0;i<3;i++) v[i] = xin[base + tid + i*256];
  float s  = v[0]+v[1]+v[2];
  float s2 = v[0]*v[0]+v[1]*v[1]+v[2]*v[2];
#pragma unroll
  for (int off=32; off; off>>=1){ s += __shfl_down(s,off); s2 += __shfl_down(s2,off); }
  __shared__ float ps[4], ps2[4], mb[2];
  if ((tid&63)==0){ ps[tid>>6]=s; ps2[tid>>6]=s2; }
  __syncthreads();
  if (tid==0){
    float S  = ps[0]+ps[1]+ps[2]+ps[3];
    float S2 = ps2[0]+ps2[1]+ps2[2]+ps2[3];
    float m  = S / (float)CD;
    float var = S2 / (float)CD - m*m;
    mb[0]=m; mb[1]=1.0f/sqrtf(var + 1e-5f);
  }
  __syncthreads();
  float m=mb[0], inv=mb[1];
#pragma unroll
  for (int i=0;i<3;i++){
    int c = tid + i*256;
    float r = (v[i]-m)*inv*gam[c] + bet[c];
    unsigned short h = f2b(r);
    outh[base+c] = h;
    if (outl) outl[base+c] = f2b(r - us2f(h));
  }
}

// ---------------- fused S=q@k^T (bf16x3) + row softmax, per z=(b,h) ----------------
__global__ __launch_bounds__(256) void sqs_k(const unsigned short* __restrict__ Qh,
                                             const unsigned short* __restrict__ Ql,
                                             const unsigned short* __restrict__ Kh,
                                             const unsigned short* __restrict__ Kl,
                                             float* __restrict__ S)
{
  __shared__ short Bh_s[SROWS*64], Bl_s[SROWS*64];
  int tid = threadIdx.x;
  int z = blockIdx.y;
  int m0 = blockIdx.x * 128;
  const unsigned short* qhz = Qh + (long)z*NTOK*DH;
  const unsigned short* qlz = Ql + (long)z*NTOK*DH;
  const unsigned short* khz = Kh + (long)z*NTOK*DH;
  const unsigned short* klz = Kl + (long)z*NTOK*DH;
  u16x8 zz = {0,0,0,0,0,0,0,0};
  for (int i = tid; i < SROWS*8; i += 256) {
    int row = i>>3, c = i&7;
    u16x8 vh = zz, vl = zz;
    if (row < NTOK) {
      vh = *(const u16x8*)(khz + (long)row*DH + c*8);
      vl = *(const u16x8*)(klz + (long)row*DH + c*8);
    }
    int off = row*64 + ((c ^ (row&7))<<3);
    *(u16x8*)&Bh_s[off] = vh;
    *(u16x8*)&Bl_s[off] = vl;
  }
  __syncthreads();
  int w = tid>>6, l = tid&63;
  int lr = l&15, hi2 = l>>4, kq = hi2*8;
  int rbase0 = m0 + (w<<5);
  floatx4 acc[2][13];
#pragma unroll
  for (int mt=0;mt<2;mt++)
#pragma unroll
    for (int nt=0;nt<13;nt++) acc[mt][nt] = (floatx4){0.f,0.f,0.f,0.f};
#pragma unroll
  for (int ks=0; ks<2; ks++){
    int k0 = ks*32;
    short8 afh[2], afl[2];
#pragma unroll
    for (int mt=0;mt<2;mt++){
      int rowA = clamp196(rbase0 + mt*16 + lr);
      long qo = (long)rowA*DH + k0 + kq;
      afh[mt] = *(const short8*)(qhz + qo);
      afl[mt] = *(const short8*)(qlz + qo);
    }
#pragma unroll
    for (int nt=0;nt<13;nt++){
      int rowB = nt*16 + lr;
      int cc = (ks<<2) + hi2;
      int off = rowB*64 + ((cc ^ (rowB&7))<<3);
      short8 bfh = *(short8*)&Bh_s[off];
      short8 bfl = *(short8*)&Bl_s[off];
#pragma unroll
      for (int mt=0;mt<2;mt++){
        acc[mt][nt] = __builtin_amdgcn_mfma_f32_16x16x32_bf16(afh[mt], bfh, acc[mt][nt], 0, 0, 0);
        acc[mt][nt] = __builtin_amdgcn_mfma_f32_16x16x32_bf16(afh[mt], bfl, acc[mt][nt], 0, 0, 0);
        acc[mt][nt] = __builtin_amdgcn_mfma_f32_16x16x32_bf16(afl[mt], bfh, acc[mt][nt], 0, 0, 0);
      }
    }
  }
  float* Sz = S + (long)z*NTOK*NTOK;
#pragma unroll
  for (int mt=0;mt<2;mt++){
#pragma unroll
    for (int r=0;r<4;r++){
      int row = rbase0 + mt*16 + hi2*4 + r;
      float ev[13];
      float mx = -3.4e38f;
#pragma unroll
      for (int nt=0;nt<13;nt++){
        int col = nt*16 + lr;
        float v = acc[mt][nt][r];
        if (col >= NTOK) v = -3.4e38f;
        ev[nt] = v;
        mx = fmaxf(mx, v);
      }
#pragma unroll
      for (int mk=1; mk<16; mk<<=1) mx = fmaxf(mx, __shfl_xor(mx, mk));
      float sum = 0.f;
#pragma unroll
      for (int nt=0;nt<13;nt++){
        float e = expf(ev[nt]-mx);
        ev[nt] = e;
        sum += e;
      }
#pragma unroll
      for (int mk=1; mk<16; mk<<=1) sum += __shfl_xor(sum, mk);
      if (row < NTOK){
#pragma unroll
        for (int nt=0;nt<13;nt++){
          int col = nt*16 + lr;
          if (col < NTOK) Sz[(long)row*NTOK + col] = ev[nt]/sum;
        }
      }
    }
  }
}

// ---------------- PV MFMA: C[197,64] = P[197,197] @ V[197,64] per z=(b,h) ----------------
struct PvP {
  const float* P;
  const unsigned short* Vt;
  unsigned short* C;
};

__global__ __launch_bounds__(256) void pv_k(PvP p)
{
  __shared__ short Ahs[128*32], Als[128*32], Bs[64*32];
  int tid = threadIdx.x;
  int z = blockIdx.z;
  int cb = z / NH, h = z - cb*NH;
  const float* Az = p.P + (long)z*NTOK*NTOK;
  const unsigned short* Bz = p.Vt + (long)z*DH*NTOK;
  int m0 = blockIdx.y*128;
  int w = tid>>6, l = tid&63;
  int wm = (w&1)*64, wn = (w>>1)*32;
  int lr = l&15, kq = (l>>4)*8;
  floatx4 acc[4][2];
#pragma unroll
  for (int i=0;i<4;i++)
#pragma unroll
    for (int j=0;j<2;j++) acc[i][j] = (floatx4){0.f,0.f,0.f,0.f};
  int r0i = tid>>2, q0 = (tid&3)*8;
  int r1i = r0i + 64;
  int w0s = swz(r0i, q0), w1s = swz(r1i, q0);
  for (int k0 = 0; k0 < NTOK; k0 += 32) {
    u16x8 ah0={0,0,0,0,0,0,0,0}, al0={0,0,0,0,0,0,0,0};
    u16x8 ah1={0,0,0,0,0,0,0,0}, al1={0,0,0,0,0,0,0,0};
    u16x8 b0 ={0,0,0,0,0,0,0,0};
    int rem = NTOK - k0 - q0;
    { int gm = m0 + r0i;
      if (gm < NTOK && rem > 0) ldsplit(Az + (long)gm*NTOK + k0 + q0, rem, ah0, al0); }
    { int gm = m0 + r1i;
      if (gm < NTOK && rem > 0) ldsplit(Az + (long)gm*NTOK + k0 + q0, rem, ah1, al1); }
    { const unsigned short* bp = Bz + (long)r0i*NTOK + k0 + q0;
      if (rem >= 8) b0 = *(const u16x8*)bp;
      else if (rem > 0) {
#pragma unroll
        for (int j=0;j<8;j++) if (j < rem) b0[j] = bp[j];
      } }
    __syncthreads();
    *(u16x8*)&Ahs[r0i*32 + w0s] = ah0;
    *(u16x8*)&Ahs[r1i*32 + w1s] = ah1;
    *(u16x8*)&Als[r0i*32 + w0s] = al0;
    *(u16x8*)&Als[r1i*32 + w1s] = al1;
    *(u16x8*)&Bs [r0i*32 + w0s] = b0;
    __syncthreads();
    short8 afh[4], afl[4], bfr[2];
#pragma unroll
    for (int mt=0;mt<4;mt++){
      int rr = wm + mt*16 + lr; int rs = rr*32 + swz(rr,kq);
      afh[mt] = *(short8*)&Ahs[rs];
      afl[mt] = *(short8*)&Als[rs];
    }
#pragma unroll
    for (int nt=0;nt<2;nt++){
      int rr = wn + nt*16 + lr;
      bfr[nt] = *(short8*)&Bs[rr*32 + swz(rr,kq)];
    }
#pragma unroll
    for (int mt=0;mt<4;mt++)
#pragma unroll
      for (int nt=0;nt<2;nt++){
        acc[mt][nt] = __builtin_amdgcn_mfma_f32_16x16x32_bf16(afh[mt], bfr[nt], acc[mt][nt], 0, 0, 0);
        acc[mt][nt] = __builtin_amdgcn_mfma_f32_16x16x32_bf16(afl[mt], bfr[nt], acc[mt][nt], 0, 0, 0);
      }
  }
  int rbase = (l>>4)*4;
#pragma unroll
  for (int mt=0;mt<4;mt++){
#pragma unroll
    for (int r=0;r<4;r++){
      int gm = m0 + wm + mt*16 + rbase + r;
      if (gm >= NTOK) continue;
#pragma unroll
      for (int nt=0;nt<2;nt++){
        int gn = wn + nt*16 + lr;   // d in 0..63
        p.C[(long)cb*NTOK*CD + (long)gm*CD + h*DH + gn] = f2b(acc[mt][nt][r]);
      }
    }
  }
}

// ---------------- bf16 MFMA GEMM (A reg-staged LDS, B frags direct from L2) ----------------
// B rows must be multiple-of-128 N (all call sites: 768/3072). EPI as before.
struct MmP {
  const unsigned short* A;
  const unsigned short* B;
  void* C;
  const float* bias;
  const float* resid;
  unsigned short* vout;
  int M, N, K, ldc;
};

template<int EPI>
__global__ __launch_bounds__(256) void mgemm_k(MmP p)
{
  __shared__ short As[128*32];
  int tid = threadIdx.x;
  int m0 = blockIdx.y*128, n0 = blockIdx.x*128;
  int w = tid>>6, l = tid&63;
  int wm = (w&1)*64, wn = (w>>1)*64;
  int lr = l&15, kq = (l>>4)*8;
  floatx4 acc[4][4];
#pragma unroll
  for (int i=0;i<4;i++)
#pragma unroll
    for (int j=0;j<4;j++) acc[i][j] = (floatx4){0.f,0.f,0.f,0.f};
  int r0i = tid>>2, q0 = (tid&3)*8;
  int r1i = r0i + 64;
  int w0s = swz(r0i, q0), w1s = swz(r1i, q0);
  // B fragment base offsets (direct L2 reads; N is exact multiple of 128)
  long bo[4];
#pragma unroll
  for (int nt=0;nt<4;nt++) bo[nt] = (long)(n0 + wn + nt*16 + lr)*p.K + kq;
  for (int k0 = 0; k0 < p.K; k0 += 32) {
    u16x8 a0 = {0,0,0,0,0,0,0,0}, a1 = {0,0,0,0,0,0,0,0};
    { int gm = m0 + r0i;
      if (gm < p.M) a0 = *(const u16x8*)(p.A + (long)gm*p.K + k0 + q0); }
    { int gm = m0 + r1i;
      if (gm < p.M) a1 = *(const u16x8*)(p.A + (long)gm*p.K + k0 + q0); }
    __syncthreads();
    *(u16x8*)&As[r0i*32 + w0s] = a0;
    *(u16x8*)&As[r1i*32 + w1s] = a1;
    __syncthreads();
    short8 af[4], bfr[4];
#pragma unroll
    for (int mt=0;mt<4;mt++){ int rr = wm + mt*16 + lr; af[mt]  = *(short8*)&As[rr*32 + swz(rr,kq)]; }
#pragma unroll
    for (int nt=0;nt<4;nt++) bfr[nt] = *(const short8*)(p.B + bo[nt] + k0);
#pragma unroll
    for (int mt=0;mt<4;mt++)
#pragma unroll
      for (int nt=0;nt<4;nt++)
        acc[mt][nt] = __builtin_amdgcn_mfma_f32_16x16x32_bf16(af[mt], bfr[nt], acc[mt][nt], 0, 0, 0);
  }
  int rbase = (l>>4)*4;   // C/D: col=lane&15, row=(lane>>4)*4+reg  [m89-verified]
#pragma unroll
  for (int mt=0;mt<4;mt++){
#pragma unroll
    for (int r=0;r<4;r++){
      int gm = m0 + wm + mt*16 + rbase + r;
      if (gm >= p.M) continue;
#pragma unroll
      for (int nt=0;nt<4;nt++){
        int gn = n0 + wn + nt*16 + lr;
        float val = acc[mt][nt][r];
        if (EPI == 1) {   // v -> vt bf16 transposed scatter [bh][d][tok]
          int cb = gm / NTOK, tok = gm - cb*NTOK;
          int h = gn >> 6, d = gn & 63;
          p.vout[(((long)cb*NH + h)*DH + d)*NTOK + tok] = f2b(val);
        } else if (EPI == 2) {
          ((float*)p.C)[(long)gm*p.ldc + gn] = val + p.bias[gn] + p.resid[(long)gm*p.ldc + gn];
        } else {
          float u = val + p.bias[gn];
          ((unsigned short*)p.C)[(long)gm*p.ldc + gn] = f2b(0.5f*u*(1.0f + erff(u*0.70710678118654752f)));
        }
      }
    }
  }
}

// ---------------- bf16x3 MFMA GEMM (A reg-staged LDS, B frags direct from L2) ----------------
struct Mm3P {
  const unsigned short *Ah, *Al, *Bh, *Bl;
  float* C;
  unsigned short *qh, *ql, *kh, *kl;
  long az, bz, cz;
  int M, N, K, ldc;
};

template<int EPI>
__global__ __launch_bounds__(256) void mgemm3_k(Mm3P p)
{
  __shared__ short Ahs[128*32], Als[128*32];
  int tid = threadIdx.x;
  int z = blockIdx.z;
  const unsigned short* Azh = p.Ah + (long)z*p.az;
  const unsigned short* Azl = p.Al + (long)z*p.az;
  const unsigned short* Bzh = p.Bh + (long)z*p.bz;
  const unsigned short* Bzl = p.Bl + (long)z*p.bz;
  int m0 = blockIdx.y*128, n0 = blockIdx.x*128;
  int w = tid>>6, l = tid&63;
  int wm = (w&1)*64, wn = (w>>1)*64;
  int lr = l&15, kq = (l>>4)*8;
  floatx4 acc[4][4];
#pragma unroll
  for (int i=0;i<4;i++)
#pragma unroll
    for (int j=0;j<4;j++) acc[i][j] = (floatx4){0.f,0.f,0.f,0.f};
  int r0i = tid>>2, q0 = (tid&3)*8;
  int r1i = r0i + 64;
  int w0s = swz(r0i, q0), w1s = swz(r1i, q0);
  long bo[4];
#pragma unroll
  for (int nt=0;nt<4;nt++) bo[nt] = (long)(n0 + wn + nt*16 + lr)*p.K + kq;
  for (int k0 = 0; k0 < p.K; k0 += 32) {
    u16x8 ah0={0,0,0,0,0,0,0,0}, al0={0,0,0,0,0,0,0,0};
    u16x8 ah1={0,0,0,0,0,0,0,0}, al1={0,0,0,0,0,0,0,0};
    { int gm = m0 + r0i;
      if (gm < p.M) {
        long o = (long)gm*p.K + k0 + q0;
        ah0 = *(const u16x8*)(Azh + o);
        al0 = *(const u16x8*)(Azl + o);
      } }
    { int gm = m0 + r1i;
      if (gm < p.M) {
        long o = (long)gm*p.K + k0 + q0;
        ah1 = *(const u16x8*)(Azh + o);
        al1 = *(const u16x8*)(Azl + o);
      } }
    __syncthreads();
    *(u16x8*)&Ahs[r0i*32 + w0s] = ah0;
    *(u16x8*)&Ahs[r1i*32 + w1s] = ah1;
    *(u16x8*)&Als[r0i*32 + w0s] = al0;
    *(u16x8*)&Als[r1i*32 + w1s] = al1;
    __syncthreads();
    short8 afh[4], afl[4], bfh[4], bfl[4];
#pragma unroll
    for (int mt=0;mt<4;mt++){
      int rr = wm + mt*16 + lr; int rs = rr*32 + swz(rr,kq);
      afh[mt] = *(short8*)&Ahs[rs];
      afl[mt] = *(short8*)&Als[rs];
    }
#pragma unroll
    for (int nt=0;nt<4;nt++){
      bfh[nt] = *(const short8*)(Bzh + bo[nt] + k0);
      bfl[nt] = *(const short8*)(Bzl + bo[nt] + k0);
    }
#pragma unroll
    for (int mt=0;mt<4;mt++)
#pragma unroll
      for (int nt=0;nt<4;nt++){
        acc[mt][nt] = __builtin_amdgcn_mfma_f32_16x16x32_bf16(afh[mt], bfh[nt], acc[mt][nt], 0, 0, 0);
        acc[mt][nt] = __builtin_amdgcn_mfma_f32_16x16x32_bf16(afh[mt], bfl[nt], acc[mt][nt], 0, 0, 0);
        acc[mt][nt] = __builtin_amdgcn_mfma_f32_16x16x32_bf16(afl[mt], bfh[nt], acc[mt][nt], 0, 0, 0);
      }
  }
  int rbase = (l>>4)*4;
#pragma unroll
  for (int mt=0;mt<4;mt++){
#pragma unroll
    for (int r=0;r<4;r++){
      int gm = m0 + wm + mt*16 + rbase + r;
      if (gm >= p.M) continue;
#pragma unroll
      for (int nt=0;nt<4;nt++){
        int gn = n0 + wn + nt*16 + lr;
        if (gn >= p.N) continue;
        float val = acc[mt][nt][r];
        if (EPI == 0) {
          p.C[(long)z*p.cz + (long)gm*p.ldc + gn] = val;
        } else {   // qk scatter, pre-split
          int which = (gn >= CD) ? 1 : 0;
          int rc = gn - which*CD;
          int hd = rc >> 6, dd = rc & 63;
          int cb = gm / NTOK, tok = gm - cb*NTOK;
          long off = (((long)cb*NH + hd)*NTOK + tok)*DH + dd;
          float v = which ? val : val*0.125f;
          unsigned short h = f2b(v);
          unsigned short lo16 = f2b(v - us2f(h));
          if (which) { p.kh[off] = h; p.kl[off] = lo16; }
          else       { p.qh[off] = h; p.ql[off] = lo16; }
        }
      }
    }
  }
}

// ---------------- token selection ----------------
__global__ __launch_bounds__(256) void select_kernel(const float* __restrict__ attn,
                                                     int* __restrict__ idx_kept,
                                                     int* __restrict__ idx_elim, int b0)
{
  int cb = blockIdx.x, tid = threadIdx.x;
  int b = b0 + cb;
  __shared__ float diag[NTOK-1];
  __shared__ int kept[NTOK];
  if (tid < NTOK-1) {
    int t = tid + 1;
    float s = 0.f;
#pragma unroll
    for (int h=0; h<NH; h++)
      s += attn[(((long)cb*NH + h)*NTOK + t)*NTOK + t];
    diag[tid] = s / 12.0f;
  }
  if (tid < KTOK) idx_kept[b*KTOK + tid] = 0;
  if (tid < RTOK) idx_elim[b*RTOK + tid] = 1;
  __syncthreads();
  if (tid < NTOK-1) {
    float dv = diag[tid];
    int r = 0;
    for (int m=0; m<NTOK-1; m++){
      float dm = diag[m];
      r += ((dm > dv) || (dm == dv && m < tid)) ? 1 : 0;
    }
    kept[tid+1] = (r < (NTOK-1-RTOK)) ? 1 : 0;
  }
  __syncthreads();
  if (tid < NTOK-1) {
    int t = tid + 1;
    if (kept[t]) {
      int pos = 1;
      for (int s2=1; s2<t; s2++) pos += kept[s2];
      if (pos >= 1 && pos < KTOK) idx_kept[b*KTOK + pos] = t;
    } else {
      int pos = 0;
      for (int s2=1; s2<t; s2++) pos += 1 - kept[s2];
      if (pos >= 0 && pos < RTOK) idx_elim[b*RTOK + pos] = t;
    }
  }
  if (tid == 0) idx_kept[b*KTOK] = 0;
}

// ---------------- fused threshold + propagation (radix-select + MFMA) ----------------
#define PNEL 38   /* ceil(9702/256) */
__global__ __launch_bounds__(256) void prop_kernel(const float* __restrict__ attn,
                                                   const float* __restrict__ x1c,
                                                   const int* __restrict__ idx_kept,
                                                   const int* __restrict__ idx_elim,
                                                   float* __restrict__ x2, int b0)
{
  int z = blockIdx.x;
  int cb = z / NH, h = z - cb*NH;
  int b = b0 + cb;
  int tid = threadIdx.x;
  int wid = tid >> 6, l = tid & 63;
  int lr = l & 15, hi2 = l >> 4;
  __shared__ short WhL[112*128];
  __shared__ short XtL[64*128];
  __shared__ unsigned hist[64];
  __shared__ int kidx[KTOK], eidx[RTOK];
  if (tid < KTOK) kidx[tid] = clamp196(idx_kept[b*KTOK + tid]);
  if (tid < RTOK) eidx[tid] = clamp196(idx_elim[b*RTOK + tid]);
  u16x8 zz = {0,0,0,0,0,0,0,0};
#pragma unroll
  for (int i=0;i<7;i++) *(u16x8*)&WhL[tid*8 + i*2048] = zz;
#pragma unroll
  for (int i=0;i<4;i++) *(u16x8*)&XtL[tid*8 + i*2048] = zz;
  __syncthreads();
  for (int i = tid; i < RTOK*DH; i += 256){
    int e = i >> 6, d = i & 63;
    float v = x1c[((long)cb*NTOK + eidx[e])*CD + h*DH + d];
    XtL[d*128 + (((e>>3) ^ (d&7))<<3) + (e&7)] = (short)f2b(v);
  }
  const float* ab = attn + (long)z*NTOK*NTOK;
  unsigned wb[PNEL];
#pragma unroll
  for (int j=0;j<PNEL;j++){
    int i = tid + (j<<8);
    if (i < WTOT){
      int k = i / RTOK, e = i - k*RTOK;
      wb[j] = __float_as_uint(ab[kidx[k]*NTOK + eidx[e]]);
    } else wb[j] = 0u;
  }
  unsigned P = 0; int rrank = THRN;
  for (int pass=0; pass<5; ++pass){
    int sh = 24 - 6*pass;
    if (tid < 64) hist[tid] = 0u;
    __syncthreads();
#pragma unroll
    for (int j=0;j<PNEL;j++){
      int i = tid + (j<<8);
      unsigned v = wb[j];
      bool m = (i < WTOT) && ((pass == 0) || ((v >> (sh+6)) == P));
      if (m) atomicAdd(&hist[(v>>sh)&63u], 1u);
    }
    __syncthreads();
    unsigned cum = 0; int bsel = 0; unsigned above = 0;
    for (int bb=63; bb>=0; --bb){
      unsigned hv = hist[bb];
      if (cum + hv >= (unsigned)rrank){ bsel = bb; above = cum; break; }
      cum += hv;
    }
    P = (P<<6) | (unsigned)bsel;
    rrank -= (int)above;
    __syncthreads();
  }
  unsigned thrbits = P;
#pragma unroll
  for (int j=0;j<PNEL;j++){
    int i = tid + (j<<8);
    if (i < WTOT){
      int k = i / RTOK, e = i - k*RTOK;
      unsigned v = (wb[j] >= thrbits) ? wb[j] : 0u;
      WhL[k*128 + (((e>>3) ^ (k&7))<<3) + (e&7)] = (short)f2b(__uint_as_float(v));
    }
  }
  __syncthreads();
  floatx4 acc[7];
#pragma unroll
  for (int mt=0;mt<7;mt++) acc[mt] = (floatx4){0.f,0.f,0.f,0.f};
  short8 bfr[4];
#pragma unroll
  for (int ks=0;ks<4;ks++){
    int c = ks*4 + hi2;
    int rd = wid*16 + lr;
    bfr[ks] = *(short8*)&XtL[rd*128 + ((c ^ (lr&7))<<3)];
  }
#pragma unroll
  for (int mt=0;mt<7;mt++){
#pragma unroll
    for (int ks=0;ks<4;ks++){
      int c = ks*4 + hi2;
      int rw = mt*16 + lr;
      short8 af = *(short8*)&WhL[rw*128 + ((c ^ (lr&7))<<3)];
      acc[mt] = __builtin_amdgcn_mfma_f32_16x16x32_bf16(af, bfr[ks], acc[mt], 0, 0, 0);
    }
  }
#pragma unroll
  for (int mt=0;mt<7;mt++){
#pragma unroll
    for (int r=0;r<4;r++){
      int kt = mt*16 + hi2*4 + r;
      if (kt >= KTOK) continue;
      int d = wid*16 + lr;
      float xk = x1c[((long)cb*NTOK + kidx[kt])*CD + h*DH + d];
      x2[((long)b*KTOK + kt)*CD + h*DH + d] = xk + 0.1f*acc[mt][r];
    }
  }
}

extern "C" void kernel_launch(void* const* d_in, const int* in_sizes, int n_in,
                              void* d_out, int out_size, void* d_ws, size_t ws_size,
                              hipStream_t stream)
{
  const float* x     = (const float*)d_in[0];
  const float* n1g   = (const float*)d_in[1];
  const float* n1b   = (const float*)d_in[2];
  const float* qkvw  = (const float*)d_in[3];
  const float* projw = (const float*)d_in[4];
  const float* projb = (const float*)d_in[5];
  const float* n2g   = (const float*)d_in[6];
  const float* n2b   = (const float*)d_in[7];
  const float* fc1w  = (const float*)d_in[8];
  const float* fc1b  = (const float*)d_in[9];
  const float* fc2w  = (const float*)d_in[10];
  const float* fc2b  = (const float*)d_in[11];
  float* out = (float*)d_out;

  const long XROW = (long)NTOK*CD;          // 151296
  const long AH   = (long)NTOK*NTOK;        // 38809
  const long AB   = (long)NH*AH;            // 465708
  const long SMALL = 6336L + 6272L;         // 12608 floats
  const long WFIX  = 1769472L;              // qkwh+qkwl+qkvwvT+projwT (floats)
  const long PB = AB + 3*XROW + XROW/2;     // floats per batch
  const long MLPFIX = 2359296L;             // fc1wT+fc2wT (floats), in chunk area
  const long MINREQ = SMALL + WFIX + (MLPFIX + 64*1920L > PB ? MLPFIX + 64*1920L : PB);

  long wsf = (long)(ws_size / 4);
  if (wsf < MINREQ) {
    float val = (float)(ws_size >> 20) * 1000.0f + 1.0f;
    fill_kernel<<<dim3((out_size+255)/256), 256, 0, stream>>>(out, out_size, val);
    return;
  }

  long avail = wsf - SMALL - WFIX;
  int G = (int)(avail / PB);
  if (G > NBATCH) G = NBATCH;
  if (G < 1) G = 1;
  long rcl = ((avail - MLPFIX) / 1920L) / 64L * 64L;
  int RC = (int)(rcl > 6336L ? 6336L : rcl);
  if (RC < 64) RC = 64;

  float* ws = (float*)d_ws;
  int*   idx_kept = (int*)ws;
  int*   idx_elim = idx_kept + 6336;
  unsigned short* qkwh   = (unsigned short*)(ws + SMALL);   // [1536][768]
  unsigned short* qkwl   = qkwh + 1179648;                  // [1536][768]
  unsigned short* qkvwvT = qkwl + 1179648;                  // [768][768]
  unsigned short* projwT = qkvwvT + 589824;                 // [768][768]
  float* base  = ws + SMALL + WFIX;
  float* attnc = base;                                      // G*AB
  // q region (G*XROW floats): pre-split q hi/lo, aliased later by x1c fp32
  unsigned short* qh = (unsigned short*)(base + (long)G*AB);
  unsigned short* ql = qh + (long)G*XROW;
  float* x1c = (float*)qh;
  // k region (G*XROW floats): pre-split k hi/lo, aliased later by aoutb bf16
  unsigned short* kh = (unsigned short*)(base + (long)G*AB + (long)G*XROW);
  unsigned short* kl = kh + (long)G*XROW;
  unsigned short* aoutb = kh;
  unsigned short* vt = (unsigned short*)(base + (long)G*AB + 2L*G*XROW);  // G*XROW/2 floats: v^T bf16 [bh][d][tok]
  // h1 region (G*XROW floats): LN1 output pre-split hi/lo
  unsigned short* h1h = (unsigned short*)(base + (long)G*AB + 2L*G*XROW + (long)G*XROW/2);
  unsigned short* h1l = h1h + (long)G*XROW;
  // MLP phase (chunk area reuse):
  unsigned short* fc1wT = (unsigned short*)base;            // [3072][768]
  unsigned short* fc2wT = fc1wT + 2359296;                  // [768][3072]
  unsigned short* h2b   = (unsigned short*)(base + MLPFIX); // RC*768
  unsigned short* gb    = h2b + (long)RC*CD;                // RC*3072

  // Phase 0: weight prep for attention
  tcast3_k<<<dim3(48,24), 256, 0, stream>>>(qkvw, CD, 3*CD, 0, qkwh, qkwl);
  tcast_k <<<dim3(24,24), 256, 0, stream>>>(qkvw, CD, 3*CD, 2*CD, qkvwvT);
  tcast_k <<<dim3(24,24), 256, 0, stream>>>(projw, CD, CD, 0, projwT);

  for (int b0 = 0; b0 < NBATCH; b0 += G) {
    int GL = (NBATCH - b0 < G) ? (NBATCH - b0) : G;
    int MROW = GL*NTOK;
    // LN1 -> h1h/h1l bf16 hi/lo
    ln_kernel<<<dim3(MROW), 256, 0, stream>>>(x + (long)b0*XROW, n1g, n1b, h1h, h1l);
    // qk bf16x3 MFMA: h1 @ qkw^T -> qh/ql (scaled), kh/kl (pre-split scatter)
    {
      Mm3P p{}; p.Ah=h1h; p.Al=h1l; p.Bh=qkwh; p.Bl=qkwl;
      p.qh=qh; p.ql=ql; p.kh=kh; p.kl=kl;
      p.M=MROW; p.N=2*CD; p.K=CD; p.ldc=0; p.az=0; p.bz=0; p.cz=0;
      mgemm3_k<1><<<dim3(12,(MROW+127)/128,1), 256, 0, stream>>>(p);
    }
    // v MFMA (single bf16): h1h @ qkvwvT^T -> vt transposed scatter (vtrans fused)
    {
      MmP p{}; p.A=h1h; p.B=qkvwvT; p.vout=vt;
      p.M=MROW; p.N=CD; p.K=CD; p.ldc=CD;
      mgemm_k<1><<<dim3(6,(MROW+127)/128,1), 256, 0, stream>>>(p);
    }
    // fused S = q @ k^T (bf16x3) + softmax -> attnc fp32
    sqs_k<<<dim3(2, GL*NH), 256, 0, stream>>>(qh, ql, kh, kl, attnc);
    select_kernel<<<dim3(GL), 256, 0, stream>>>(attnc, idx_kept, idx_elim, b0);
    // attn @ v via MFMA (A split hi/lo at stage, B = vt bf16) -> aoutb bf16
    {
      PvP p{}; p.P=attnc; p.Vt=vt; p.C=aoutb;
      pv_k<<<dim3(1,2,GL*NH), 256, 0, stream>>>(p);
    }
    // proj MFMA: x1c = x + aoutb @ projwT^T + proj_b (fp32)
    {
      MmP p{}; p.A=aoutb; p.B=projwT; p.C=x1c;
      p.M=MROW; p.N=CD; p.K=CD; p.ldc=CD;
      p.bias=projb; p.resid=x + (long)b0*XROW;
      mgemm_k<2><<<dim3(6,(MROW+127)/128,1), 256, 0, stream>>>(p);
    }
    // fused threshold + propagation -> x2 (f32) in d_out
    prop_kernel<<<dim3(GL*NH), 256, 0, stream>>>(attnc, x1c, idx_kept, idx_elim, out, b0);
  }

  // ---- MLP weight prep (chunk area now free) ----
  tcast_k<<<dim3(96,24), 256, 0, stream>>>(fc1w, CD, 4*CD, 0, fc1wT);
  tcast_k<<<dim3(24,96), 256, 0, stream>>>(fc2w, 4*CD, CD, 0, fc2wT);

  // ---- MLP, row-chunked; x2 lives in d_out (f32), fc2 overwrites in place ----
  for (int r0 = 0; r0 < NBATCH*KTOK; r0 += RC) {
    int RCL = (NBATCH*KTOK - r0 < RC) ? (NBATCH*KTOK - r0) : RC;
    ln_kernel<<<dim3(RCL), 256, 0, stream>>>(out + (long)r0*CD, n2g, n2b, h2b, nullptr);
    {
      MmP p{}; p.A=h2b; p.B=fc1wT; p.C=gb;
      p.M=RCL; p.N=4*CD; p.K=CD; p.ldc=4*CD; p.bias=fc1b;
      mgemm_k<3><<<dim3(24,(RCL+127)/128,1), 256, 0, stream>>>(p);
    }
    {
      MmP p{}; p.A=gb; p.B=fc2wT; p.C=out + (long)r0*CD;
      p.M=RCL; p.N=CD; p.K=4*CD; p.ldc=CD;
      p.bias=fc2b; p.resid=out + (long)r0*CD;
      mgemm_k<2><<<dim3(6,(RCL+127)/128,1), 256, 0, stream>>>(p);
    }
  }
}

// Round 10
// 729.980 us; speedup vs baseline: 1.2288x; 1.2288x over previous
//
#include <hip/hip_runtime.h>
#include <math.h>

#define NTOK 197
#define CD   768
#define NH   12
#define DH   64
#define NBATCH 64
#define RTOK 98
#define KTOK 99
#define THRN 1941   /* count(w >= thr) >= thr_idx+1 = 1941 */
#define WTOT (KTOK*RTOK)   /* 9702 */
#define SROWS 208

typedef __attribute__((ext_vector_type(8))) short short8;
typedef __attribute__((ext_vector_type(8))) unsigned short u16x8;
typedef __attribute__((ext_vector_type(4))) float floatx4;

__device__ __forceinline__ int clamp196(int v){ return ((unsigned)v > 196u) ? 196 : v; }
__device__ __forceinline__ unsigned short f2b(float f){
  unsigned u = __float_as_uint(f);
  return (unsigned short)((u + 0x7FFFu + ((u>>16)&1u)) >> 16);
}
__device__ __forceinline__ float us2f(unsigned short u){ return __uint_as_float(((unsigned)u)<<16); }
// LDS chunk swizzle for short[row][32] tiles: XOR 16B-chunk index with (row>>1)&3.
__device__ __forceinline__ int swz(int row, int q){ return q ^ (((row>>1)&3)<<3); }

// load up to 8 fp32 (rem valid), cast to bf16 (round-to-nearest)
__device__ __forceinline__ void ldcvt(const float* ap, int rem, u16x8& h){
  float v[8];
  if (rem >= 8) {
    float4 t0 = *(const float4*)ap, t1 = *(const float4*)(ap+4);
    v[0]=t0.x; v[1]=t0.y; v[2]=t0.z; v[3]=t0.w;
    v[4]=t1.x; v[5]=t1.y; v[6]=t1.z; v[7]=t1.w;
  } else {
#pragma unroll
    for (int j=0;j<8;j++) v[j] = (j < rem) ? ap[j] : 0.f;
  }
#pragma unroll
  for (int j=0;j<8;j++) h[j] = f2b(v[j]);
}

// ---------------- diagnostic fill ----------------
__global__ __launch_bounds__(256) void fill_kernel(float* __restrict__ out, int n, float val)
{
  int i = blockIdx.x*256 + threadIdx.x;
  if (i < n) out[i] = val;
}

// ---------------- transpose+cast: dst[n][k] = bf16(src[k][col0+n]) ----------------
__global__ __launch_bounds__(256) void tcast_k(const float* __restrict__ src, int K, int ldn, int col0,
                                               unsigned short* __restrict__ dst)
{
  __shared__ float t[32][33];
  int n0 = blockIdx.x*32, k0 = blockIdx.y*32;
  int lx = threadIdx.x & 31, ly = threadIdx.x >> 5;
#pragma unroll
  for (int i=0;i<4;i++)
    t[ly + i*8][lx] = src[(long)(k0 + ly + i*8)*ldn + col0 + n0 + lx];
  __syncthreads();
#pragma unroll
  for (int i=0;i<4;i++){
    int n = ly + i*8;
    dst[(long)(n0 + n)*K + k0 + lx] = f2b(t[lx][n]);
  }
}

// ---------------- transpose + hi/lo split ----------------
__global__ __launch_bounds__(256) void tcast3_k(const float* __restrict__ src, int K, int ldn, int col0,
                                                unsigned short* __restrict__ dsth,
                                                unsigned short* __restrict__ dstl)
{
  __shared__ float t[32][33];
  int n0 = blockIdx.x*32, k0 = blockIdx.y*32;
  int lx = threadIdx.x & 31, ly = threadIdx.x >> 5;
#pragma unroll
  for (int i=0;i<4;i++)
    t[ly + i*8][lx] = src[(long)(k0 + ly + i*8)*ldn + col0 + n0 + lx];
  __syncthreads();
#pragma unroll
  for (int i=0;i<4;i++){
    int n = ly + i*8;
    float v = t[lx][n];
    unsigned short h = f2b(v);
    dsth[(long)(n0 + n)*K + k0 + lx] = h;
    dstl[(long)(n0 + n)*K + k0 + lx] = f2b(v - us2f(h));
  }
}

// ---------------- LayerNorm (row 768; bf16 hi (+ optional lo) out) ----------------
__global__ __launch_bounds__(256) void ln_kernel(const float* __restrict__ xin,
                                                 const float* __restrict__ gam,
                                                 const float* __restrict__ bet,
                                                 unsigned short* __restrict__ outh,
                                                 unsigned short* __restrict__ outl)
{
  int row = blockIdx.x;
  int tid = threadIdx.x;
  long base = (long)row * CD;
  float v[3];
#pragma unroll
  for (int i=0;i<3;i++) v[i] = xin[base + tid + i*256];
  float s  = v[0]+v[1]+v[2];
  float s2 = v[0]*v[0]+v[1]*v[1]+v[2]*v[2];
#pragma unroll
  for (int off=32; off; off>>=1){ s += __shfl_down(s,off); s2 += __shfl_down(s2,off); }
  __shared__ float ps[4], ps2[4], mb[2];
  if ((tid&63)==0){ ps[tid>>6]=s; ps2[tid>>6]=s2; }
  __syncthreads();
  if (tid==0){
    float S  = ps[0]+ps[1]+ps[2]+ps[3];
    float S2 = ps2[0]+ps2[1]+ps2[2]+ps2[3];
    float m  = S / (float)CD;
    float var = S2 / (float)CD - m*m;
    mb[0]=m; mb[1]=1.0f/sqrtf(var + 1e-5f);
  }
  __syncthreads();
  float m=mb[0], inv=mb[1];
#pragma unroll
  for (int i=0;i<3;i++){
    int c = tid + i*256;
    float r = (v[i]-m)*inv*gam[c] + bet[c];
    unsigned short h = f2b(r);
    outh[base+c] = h;
    if (outl) outl[base+c] = f2b(r - us2f(h));
  }
}

// ---------------- fused S=q@k^T (bf16x3) + row softmax, per z=(b,h) ----------------
__global__ __launch_bounds__(256) void sqs_k(const unsigned short* __restrict__ Qh,
                                             const unsigned short* __restrict__ Ql,
                                             const unsigned short* __restrict__ Kh,
                                             const unsigned short* __restrict__ Kl,
                                             float* __restrict__ S)
{
  __shared__ short Bh_s[SROWS*64], Bl_s[SROWS*64];
  int tid = threadIdx.x;
  int z = blockIdx.y;
  int m0 = blockIdx.x * 128;
  const unsigned short* qhz = Qh + (long)z*NTOK*DH;
  const unsigned short* qlz = Ql + (long)z*NTOK*DH;
  const unsigned short* khz = Kh + (long)z*NTOK*DH;
  const unsigned short* klz = Kl + (long)z*NTOK*DH;
  u16x8 zz = {0,0,0,0,0,0,0,0};
  for (int i = tid; i < SROWS*8; i += 256) {
    int row = i>>3, c = i&7;
    u16x8 vh = zz, vl = zz;
    if (row < NTOK) {
      vh = *(const u16x8*)(khz + (long)row*DH + c*8);
      vl = *(const u16x8*)(klz + (long)row*DH + c*8);
    }
    int off = row*64 + ((c ^ (row&7))<<3);
    *(u16x8*)&Bh_s[off] = vh;
    *(u16x8*)&Bl_s[off] = vl;
  }
  __syncthreads();
  int w = tid>>6, l = tid&63;
  int lr = l&15, hi2 = l>>4, kq = hi2*8;
  int rbase0 = m0 + (w<<5);
  floatx4 acc[2][13];
#pragma unroll
  for (int mt=0;mt<2;mt++)
#pragma unroll
    for (int nt=0;nt<13;nt++) acc[mt][nt] = (floatx4){0.f,0.f,0.f,0.f};
#pragma unroll
  for (int ks=0; ks<2; ks++){
    int k0 = ks*32;
    short8 afh[2], afl[2];
#pragma unroll
    for (int mt=0;mt<2;mt++){
      int rowA = clamp196(rbase0 + mt*16 + lr);
      long qo = (long)rowA*DH + k0 + kq;
      afh[mt] = *(const short8*)(qhz + qo);
      afl[mt] = *(const short8*)(qlz + qo);
    }
#pragma unroll
    for (int nt=0;nt<13;nt++){
      int rowB = nt*16 + lr;
      int cc = (ks<<2) + hi2;
      int off = rowB*64 + ((cc ^ (rowB&7))<<3);
      short8 bfh = *(short8*)&Bh_s[off];
      short8 bfl = *(short8*)&Bl_s[off];
#pragma unroll
      for (int mt=0;mt<2;mt++){
        acc[mt][nt] = __builtin_amdgcn_mfma_f32_16x16x32_bf16(afh[mt], bfh, acc[mt][nt], 0, 0, 0);
        acc[mt][nt] = __builtin_amdgcn_mfma_f32_16x16x32_bf16(afh[mt], bfl, acc[mt][nt], 0, 0, 0);
        acc[mt][nt] = __builtin_amdgcn_mfma_f32_16x16x32_bf16(afl[mt], bfh, acc[mt][nt], 0, 0, 0);
      }
    }
  }
  float* Sz = S + (long)z*NTOK*NTOK;
#pragma unroll
  for (int mt=0;mt<2;mt++){
#pragma unroll
    for (int r=0;r<4;r++){
      int row = rbase0 + mt*16 + hi2*4 + r;
      float ev[13];
      float mx = -3.4e38f;
#pragma unroll
      for (int nt=0;nt<13;nt++){
        int col = nt*16 + lr;
        float v = acc[mt][nt][r];
        if (col >= NTOK) v = -3.4e38f;
        ev[nt] = v;
        mx = fmaxf(mx, v);
      }
#pragma unroll
      for (int mk=1; mk<16; mk<<=1) mx = fmaxf(mx, __shfl_xor(mx, mk));
      float sum = 0.f;
#pragma unroll
      for (int nt=0;nt<13;nt++){
        float e = expf(ev[nt]-mx);
        ev[nt] = e;
        sum += e;
      }
#pragma unroll
      for (int mk=1; mk<16; mk<<=1) sum += __shfl_xor(sum, mk);
      if (row < NTOK){
#pragma unroll
        for (int nt=0;nt<13;nt++){
          int col = nt*16 + lr;
          if (col < NTOK) Sz[(long)row*NTOK + col] = ev[nt]/sum;
        }
      }
    }
  }
}

// ---------------- PV MFMA: C[197,64] = P[197,197] @ V[197,64] per z=(b,h) ----------------
// A = P cast to single bf16 at stage (P in [0,1], rows sum to 1 -> rounding error
// ~2^-9 relative, dominated by aoutb's own bf16 rounding); B = vt bf16 [z][64][197].
struct PvP {
  const float* P;
  const unsigned short* Vt;
  unsigned short* C;
};

__global__ __launch_bounds__(256) void pv_k(PvP p)
{
  __shared__ short Ahs[128*32], Bs[64*32];
  int tid = threadIdx.x;
  int z = blockIdx.z;
  int cb = z / NH, h = z - cb*NH;
  const float* Az = p.P + (long)z*NTOK*NTOK;
  const unsigned short* Bz = p.Vt + (long)z*DH*NTOK;
  int m0 = blockIdx.y*128;
  int w = tid>>6, l = tid&63;
  int wm = (w&1)*64, wn = (w>>1)*32;
  int lr = l&15, kq = (l>>4)*8;
  floatx4 acc[4][2];
#pragma unroll
  for (int i=0;i<4;i++)
#pragma unroll
    for (int j=0;j<2;j++) acc[i][j] = (floatx4){0.f,0.f,0.f,0.f};
  int r0i = tid>>2, q0 = (tid&3)*8;
  int r1i = r0i + 64;
  int w0s = swz(r0i, q0), w1s = swz(r1i, q0);
  for (int k0 = 0; k0 < NTOK; k0 += 32) {
    u16x8 ah0={0,0,0,0,0,0,0,0};
    u16x8 ah1={0,0,0,0,0,0,0,0};
    u16x8 b0 ={0,0,0,0,0,0,0,0};
    int rem = NTOK - k0 - q0;
    { int gm = m0 + r0i;
      if (gm < NTOK && rem > 0) ldcvt(Az + (long)gm*NTOK + k0 + q0, rem, ah0); }
    { int gm = m0 + r1i;
      if (gm < NTOK && rem > 0) ldcvt(Az + (long)gm*NTOK + k0 + q0, rem, ah1); }
    { const unsigned short* bp = Bz + (long)r0i*NTOK + k0 + q0;
      if (rem >= 8) b0 = *(const u16x8*)bp;
      else if (rem > 0) {
#pragma unroll
        for (int j=0;j<8;j++) if (j < rem) b0[j] = bp[j];
      } }
    __syncthreads();
    *(u16x8*)&Ahs[r0i*32 + w0s] = ah0;
    *(u16x8*)&Ahs[r1i*32 + w1s] = ah1;
    *(u16x8*)&Bs [r0i*32 + w0s] = b0;
    __syncthreads();
    short8 afh[4], bfr[2];
#pragma unroll
    for (int mt=0;mt<4;mt++){
      int rr = wm + mt*16 + lr;
      afh[mt] = *(short8*)&Ahs[rr*32 + swz(rr,kq)];
    }
#pragma unroll
    for (int nt=0;nt<2;nt++){
      int rr = wn + nt*16 + lr;
      bfr[nt] = *(short8*)&Bs[rr*32 + swz(rr,kq)];
    }
#pragma unroll
    for (int mt=0;mt<4;mt++)
#pragma unroll
      for (int nt=0;nt<2;nt++)
        acc[mt][nt] = __builtin_amdgcn_mfma_f32_16x16x32_bf16(afh[mt], bfr[nt], acc[mt][nt], 0, 0, 0);
  }
  int rbase = (l>>4)*4;
#pragma unroll
  for (int mt=0;mt<4;mt++){
#pragma unroll
    for (int r=0;r<4;r++){
      int gm = m0 + wm + mt*16 + rbase + r;
      if (gm >= NTOK) continue;
#pragma unroll
      for (int nt=0;nt<2;nt++){
        int gn = wn + nt*16 + lr;   // d in 0..63
        p.C[(long)cb*NTOK*CD + (long)gm*CD + h*DH + gn] = f2b(acc[mt][nt][r]);
      }
    }
  }
}

// ---------------- bf16 MFMA GEMM (reg-staged, BK=32) ----------------
// EPI 1: v -> vt bf16 transposed scatter [bh][d][tok] (fuses the old vtrans pass)
struct MmP {
  const unsigned short* A;
  const unsigned short* B;
  void* C;
  const float* bias;
  const float* resid;
  unsigned short* vout;
  int M, N, K, ldc;
};

template<int EPI>
__global__ __launch_bounds__(256) void mgemm_k(MmP p)
{
  __shared__ short As[128*32];
  __shared__ short Bs[128*32];
  int tid = threadIdx.x;
  int m0 = blockIdx.y*128, n0 = blockIdx.x*128;
  int w = tid>>6, l = tid&63;
  int wm = (w&1)*64, wn = (w>>1)*64;
  int lr = l&15, kq = (l>>4)*8;
  floatx4 acc[4][4];
#pragma unroll
  for (int i=0;i<4;i++)
#pragma unroll
    for (int j=0;j<4;j++) acc[i][j] = (floatx4){0.f,0.f,0.f,0.f};
  int r0i = tid>>2, q0 = (tid&3)*8;
  int r1i = r0i + 64;
  int w0s = swz(r0i, q0), w1s = swz(r1i, q0);
  for (int k0 = 0; k0 < p.K; k0 += 32) {
    u16x8 a0 = {0,0,0,0,0,0,0,0}, a1 = {0,0,0,0,0,0,0,0};
    { int gm = m0 + r0i;
      if (gm < p.M) a0 = *(const u16x8*)(p.A + (long)gm*p.K + k0 + q0); }
    { int gm = m0 + r1i;
      if (gm < p.M) a1 = *(const u16x8*)(p.A + (long)gm*p.K + k0 + q0); }
    u16x8 b0 = *(const u16x8*)(p.B + (long)(n0 + r0i)*p.K + k0 + q0);
    u16x8 b1 = *(const u16x8*)(p.B + (long)(n0 + r1i)*p.K + k0 + q0);
    __syncthreads();
    *(u16x8*)&As[r0i*32 + w0s] = a0;
    *(u16x8*)&As[r1i*32 + w1s] = a1;
    *(u16x8*)&Bs[r0i*32 + w0s] = b0;
    *(u16x8*)&Bs[r1i*32 + w1s] = b1;
    __syncthreads();
    short8 af[4], bfr[4];
#pragma unroll
    for (int mt=0;mt<4;mt++){ int rr = wm + mt*16 + lr; af[mt]  = *(short8*)&As[rr*32 + swz(rr,kq)]; }
#pragma unroll
    for (int nt=0;nt<4;nt++){ int rr = wn + nt*16 + lr; bfr[nt] = *(short8*)&Bs[rr*32 + swz(rr,kq)]; }
#pragma unroll
    for (int mt=0;mt<4;mt++)
#pragma unroll
      for (int nt=0;nt<4;nt++)
        acc[mt][nt] = __builtin_amdgcn_mfma_f32_16x16x32_bf16(af[mt], bfr[nt], acc[mt][nt], 0, 0, 0);
  }
  int rbase = (l>>4)*4;   // C/D: col=lane&15, row=(lane>>4)*4+reg  [m89-verified]
#pragma unroll
  for (int mt=0;mt<4;mt++){
#pragma unroll
    for (int r=0;r<4;r++){
      int gm = m0 + wm + mt*16 + rbase + r;
      if (gm >= p.M) continue;
#pragma unroll
      for (int nt=0;nt<4;nt++){
        int gn = n0 + wn + nt*16 + lr;
        float val = acc[mt][nt][r];
        if (EPI == 1) {   // v -> vt bf16 transposed scatter [bh][d][tok]
          int cb = gm / NTOK, tok = gm - cb*NTOK;
          int h = gn >> 6, d = gn & 63;
          p.vout[(((long)cb*NH + h)*DH + d)*NTOK + tok] = f2b(val);
        } else if (EPI == 2) {
          ((float*)p.C)[(long)gm*p.ldc + gn] = val + p.bias[gn] + p.resid[(long)gm*p.ldc + gn];
        } else {
          float u = val + p.bias[gn];
          ((unsigned short*)p.C)[(long)gm*p.ldc + gn] = f2b(0.5f*u*(1.0f + erff(u*0.70710678118654752f)));
        }
      }
    }
  }
}

// ---------------- bf16x3 MFMA GEMM (reg-staged, BK=32) ----------------
struct Mm3P {
  const unsigned short *Ah, *Al, *Bh, *Bl;
  float* C;
  unsigned short *qh, *ql, *kh, *kl;
  long az, bz, cz;
  int M, N, K, ldc;
};

template<int EPI>
__global__ __launch_bounds__(256) void mgemm3_k(Mm3P p)
{
  __shared__ short Ahs[128*32], Als[128*32], Bhs[128*32], Bls[128*32];
  int tid = threadIdx.x;
  int z = blockIdx.z;
  const unsigned short* Azh = p.Ah + (long)z*p.az;
  const unsigned short* Azl = p.Al + (long)z*p.az;
  const unsigned short* Bzh = p.Bh + (long)z*p.bz;
  const unsigned short* Bzl = p.Bl + (long)z*p.bz;
  int m0 = blockIdx.y*128, n0 = blockIdx.x*128;
  int w = tid>>6, l = tid&63;
  int wm = (w&1)*64, wn = (w>>1)*64;
  int lr = l&15, kq = (l>>4)*8;
  floatx4 acc[4][4];
#pragma unroll
  for (int i=0;i<4;i++)
#pragma unroll
    for (int j=0;j<4;j++) acc[i][j] = (floatx4){0.f,0.f,0.f,0.f};
  int r0i = tid>>2, q0 = (tid&3)*8;
  int r1i = r0i + 64;
  int w0s = swz(r0i, q0), w1s = swz(r1i, q0);
  for (int k0 = 0; k0 < p.K; k0 += 32) {
    u16x8 ah0={0,0,0,0,0,0,0,0}, al0={0,0,0,0,0,0,0,0};
    u16x8 ah1={0,0,0,0,0,0,0,0}, al1={0,0,0,0,0,0,0,0};
    u16x8 bh0={0,0,0,0,0,0,0,0}, bl0={0,0,0,0,0,0,0,0};
    u16x8 bh1={0,0,0,0,0,0,0,0}, bl1={0,0,0,0,0,0,0,0};
    { int gm = m0 + r0i;
      if (gm < p.M) {
        long o = (long)gm*p.K + k0 + q0;
        ah0 = *(const u16x8*)(Azh + o);
        al0 = *(const u16x8*)(Azl + o);
      } }
    { int gm = m0 + r1i;
      if (gm < p.M) {
        long o = (long)gm*p.K + k0 + q0;
        ah1 = *(const u16x8*)(Azh + o);
        al1 = *(const u16x8*)(Azl + o);
      } }
    { int gn = n0 + r0i;
      if (gn < p.N) {
        long o = (long)gn*p.K + k0 + q0;
        bh0 = *(const u16x8*)(Bzh + o);
        bl0 = *(const u16x8*)(Bzl + o);
      } }
    { int gn = n0 + r1i;
      if (gn < p.N) {
        long o = (long)gn*p.K + k0 + q0;
        bh1 = *(const u16x8*)(Bzh + o);
        bl1 = *(const u16x8*)(Bzl + o);
      } }
    __syncthreads();
    *(u16x8*)&Ahs[r0i*32 + w0s] = ah0;
    *(u16x8*)&Ahs[r1i*32 + w1s] = ah1;
    *(u16x8*)&Als[r0i*32 + w0s] = al0;
    *(u16x8*)&Als[r1i*32 + w1s] = al1;
    *(u16x8*)&Bhs[r0i*32 + w0s] = bh0;
    *(u16x8*)&Bhs[r1i*32 + w1s] = bh1;
    *(u16x8*)&Bls[r0i*32 + w0s] = bl0;
    *(u16x8*)&Bls[r1i*32 + w1s] = bl1;
    __syncthreads();
    short8 afh[4], afl[4], bfh[4], bfl[4];
#pragma unroll
    for (int mt=0;mt<4;mt++){
      int rr = wm + mt*16 + lr; int rs = rr*32 + swz(rr,kq);
      afh[mt] = *(short8*)&Ahs[rs];
      afl[mt] = *(short8*)&Als[rs];
    }
#pragma unroll
    for (int nt=0;nt<4;nt++){
      int rr = wn + nt*16 + lr; int rs = rr*32 + swz(rr,kq);
      bfh[nt] = *(short8*)&Bhs[rs];
      bfl[nt] = *(short8*)&Bls[rs];
    }
#pragma unroll
    for (int mt=0;mt<4;mt++)
#pragma unroll
      for (int nt=0;nt<4;nt++){
        acc[mt][nt] = __builtin_amdgcn_mfma_f32_16x16x32_bf16(afh[mt], bfh[nt], acc[mt][nt], 0, 0, 0);
        acc[mt][nt] = __builtin_amdgcn_mfma_f32_16x16x32_bf16(afh[mt], bfl[nt], acc[mt][nt], 0, 0, 0);
        acc[mt][nt] = __builtin_amdgcn_mfma_f32_16x16x32_bf16(afl[mt], bfh[nt], acc[mt][nt], 0, 0, 0);
      }
  }
  int rbase = (l>>4)*4;
#pragma unroll
  for (int mt=0;mt<4;mt++){
#pragma unroll
    for (int r=0;r<4;r++){
      int gm = m0 + wm + mt*16 + rbase + r;
      if (gm >= p.M) continue;
#pragma unroll
      for (int nt=0;nt<4;nt++){
        int gn = n0 + wn + nt*16 + lr;
        if (gn >= p.N) continue;
        float val = acc[mt][nt][r];
        if (EPI == 0) {
          p.C[(long)z*p.cz + (long)gm*p.ldc + gn] = val;
        } else {   // qk scatter, pre-split
          int which = (gn >= CD) ? 1 : 0;
          int rc = gn - which*CD;
          int hd = rc >> 6, dd = rc & 63;
          int cb = gm / NTOK, tok = gm - cb*NTOK;
          long off = (((long)cb*NH + hd)*NTOK + tok)*DH + dd;
          float v = which ? val : val*0.125f;
          unsigned short h = f2b(v);
          unsigned short lo16 = f2b(v - us2f(h));
          if (which) { p.kh[off] = h; p.kl[off] = lo16; }
          else       { p.qh[off] = h; p.ql[off] = lo16; }
        }
      }
    }
  }
}

// ---------------- token selection ----------------
__global__ __launch_bounds__(256) void select_kernel(const float* __restrict__ attn,
                                                     int* __restrict__ idx_kept,
                                                     int* __restrict__ idx_elim, int b0)
{
  int cb = blockIdx.x, tid = threadIdx.x;
  int b = b0 + cb;
  __shared__ float diag[NTOK-1];
  __shared__ int kept[NTOK];
  if (tid < NTOK-1) {
    int t = tid + 1;
    float s = 0.f;
#pragma unroll
    for (int h=0; h<NH; h++)
      s += attn[(((long)cb*NH + h)*NTOK + t)*NTOK + t];
    diag[tid] = s / 12.0f;
  }
  if (tid < KTOK) idx_kept[b*KTOK + tid] = 0;
  if (tid < RTOK) idx_elim[b*RTOK + tid] = 1;
  __syncthreads();
  if (tid < NTOK-1) {
    float dv = diag[tid];
    int r = 0;
    for (int m=0; m<NTOK-1; m++){
      float dm = diag[m];
      r += ((dm > dv) || (dm == dv && m < tid)) ? 1 : 0;
    }
    kept[tid+1] = (r < (NTOK-1-RTOK)) ? 1 : 0;
  }
  __syncthreads();
  if (tid < NTOK-1) {
    int t = tid + 1;
    if (kept[t]) {
      int pos = 1;
      for (int s2=1; s2<t; s2++) pos += kept[s2];
      if (pos >= 1 && pos < KTOK) idx_kept[b*KTOK + pos] = t;
    } else {
      int pos = 0;
      for (int s2=1; s2<t; s2++) pos += 1 - kept[s2];
      if (pos >= 0 && pos < RTOK) idx_elim[b*RTOK + pos] = t;
    }
  }
  if (tid == 0) idx_kept[b*KTOK] = 0;
}

// ---------------- fused threshold + propagation (radix-select + MFMA) ----------------
#define PNEL 38   /* ceil(9702/256) */
__global__ __launch_bounds__(256) void prop_kernel(const float* __restrict__ attn,
                                                   const float* __restrict__ x1c,
                                                   const int* __restrict__ idx_kept,
                                                   const int* __restrict__ idx_elim,
                                                   float* __restrict__ x2, int b0)
{
  int z = blockIdx.x;
  int cb = z / NH, h = z - cb*NH;
  int b = b0 + cb;
  int tid = threadIdx.x;
  int wid = tid >> 6, l = tid & 63;
  int lr = l & 15, hi2 = l >> 4;
  __shared__ short WhL[112*128];
  __shared__ short XtL[64*128];
  __shared__ unsigned hist[64];
  __shared__ int kidx[KTOK], eidx[RTOK];
  if (tid < KTOK) kidx[tid] = clamp196(idx_kept[b*KTOK + tid]);
  if (tid < RTOK) eidx[tid] = clamp196(idx_elim[b*RTOK + tid]);
  u16x8 zz = {0,0,0,0,0,0,0,0};
#pragma unroll
  for (int i=0;i<7;i++) *(u16x8*)&WhL[tid*8 + i*2048] = zz;
#pragma unroll
  for (int i=0;i<4;i++) *(u16x8*)&XtL[tid*8 + i*2048] = zz;
  __syncthreads();
  for (int i = tid; i < RTOK*DH; i += 256){
    int e = i >> 6, d = i & 63;
    float v = x1c[((long)cb*NTOK + eidx[e])*CD + h*DH + d];
    XtL[d*128 + (((e>>3) ^ (d&7))<<3) + (e&7)] = (short)f2b(v);
  }
  const float* ab = attn + (long)z*NTOK*NTOK;
  unsigned wb[PNEL];
#pragma unroll
  for (int j=0;j<PNEL;j++){
    int i = tid + (j<<8);
    if (i < WTOT){
      int k = i / RTOK, e = i - k*RTOK;
      wb[j] = __float_as_uint(ab[kidx[k]*NTOK + eidx[e]]);
    } else wb[j] = 0u;
  }
  // radix-select (exact THRN-th largest bits) with ballot match-any histogram:
  // bit-identical counts, one LDS atomic per distinct bin per wave.
  unsigned P = 0; int rrank = THRN;
  for (int pass=0; pass<5; ++pass){
    int sh = 24 - 6*pass;
    if (tid < 64) hist[tid] = 0u;
    __syncthreads();
#pragma unroll
    for (int j=0;j<PNEL;j++){
      int i = tid + (j<<8);
      unsigned v = wb[j];
      bool act = (i < WTOT) && ((pass == 0) || ((v >> (sh+6)) == P));
      unsigned bin = (v>>sh)&63u;
      unsigned long long am = __ballot(act);
      if (am == 0ull) continue;
      unsigned long long m = am;
#pragma unroll
      for (int bb2=0;bb2<6;bb2++){
        unsigned long long bm = __ballot(act && ((bin>>bb2)&1u));
        m &= ((bin>>bb2)&1u) ? bm : ~bm;
      }
      if (act){
        int ldr = __ffsll(m) - 1;
        if ((tid&63) == ldr) atomicAdd(&hist[bin], (unsigned)__popcll(m));
      }
    }
    __syncthreads();
    unsigned cum = 0; int bsel = 0; unsigned above = 0;
    for (int bb=63; bb>=0; --bb){
      unsigned hv = hist[bb];
      if (cum + hv >= (unsigned)rrank){ bsel = bb; above = cum; break; }
      cum += hv;
    }
    P = (P<<6) | (unsigned)bsel;
    rrank -= (int)above;
    __syncthreads();
  }
  unsigned thrbits = P;
#pragma unroll
  for (int j=0;j<PNEL;j++){
    int i = tid + (j<<8);
    if (i < WTOT){
      int k = i / RTOK, e = i - k*RTOK;
      unsigned v = (wb[j] >= thrbits) ? wb[j] : 0u;
      WhL[k*128 + (((e>>3) ^ (k&7))<<3) + (e&7)] = (short)f2b(__uint_as_float(v));
    }
  }
  __syncthreads();
  floatx4 acc[7];
#pragma unroll
  for (int mt=0;mt<7;mt++) acc[mt] = (floatx4){0.f,0.f,0.f,0.f};
  short8 bfr[4];
#pragma unroll
  for (int ks=0;ks<4;ks++){
    int c = ks*4 + hi2;
    int rd = wid*16 + lr;
    bfr[ks] = *(short8*)&XtL[rd*128 + ((c ^ (lr&7))<<3)];
  }
#pragma unroll
  for (int mt=0;mt<7;mt++){
#pragma unroll
    for (int ks=0;ks<4;ks++){
      int c = ks*4 + hi2;
      int rw = mt*16 + lr;
      short8 af = *(short8*)&WhL[rw*128 + ((c ^ (lr&7))<<3)];
      acc[mt] = __builtin_amdgcn_mfma_f32_16x16x32_bf16(af, bfr[ks], acc[mt], 0, 0, 0);
    }
  }
#pragma unroll
  for (int mt=0;mt<7;mt++){
#pragma unroll
    for (int r=0;r<4;r++){
      int kt = mt*16 + hi2*4 + r;
      if (kt >= KTOK) continue;
      int d = wid*16 + lr;
      float xk = x1c[((long)cb*NTOK + kidx[kt])*CD + h*DH + d];
      x2[((long)b*KTOK + kt)*CD + h*DH + d] = xk + 0.1f*acc[mt][r];
    }
  }
}

extern "C" void kernel_launch(void* const* d_in, const int* in_sizes, int n_in,
                              void* d_out, int out_size, void* d_ws, size_t ws_size,
                              hipStream_t stream)
{
  const float* x     = (const float*)d_in[0];
  const float* n1g   = (const float*)d_in[1];
  const float* n1b   = (const float*)d_in[2];
  const float* qkvw  = (const float*)d_in[3];
  const float* projw = (const float*)d_in[4];
  const float* projb = (const float*)d_in[5];
  const float* n2g   = (const float*)d_in[6];
  const float* n2b   = (const float*)d_in[7];
  const float* fc1w  = (const float*)d_in[8];
  const float* fc1b  = (const float*)d_in[9];
  const float* fc2w  = (const float*)d_in[10];
  const float* fc2b  = (const float*)d_in[11];
  float* out = (float*)d_out;

  const long XROW = (long)NTOK*CD;          // 151296
  const long AH   = (long)NTOK*NTOK;        // 38809
  const long AB   = (long)NH*AH;            // 465708
  const long SMALL = 6336L + 6272L;         // 12608 floats
  const long WFIX  = 1769472L;              // qkwh+qkwl+qkvwvT+projwT (floats)
  const long PB = AB + 3*XROW + XROW/2;     // floats per batch
  const long MLPFIX = 2359296L;             // fc1wT+fc2wT (floats), in chunk area
  const long MINREQ = SMALL + WFIX + (MLPFIX + 64*1920L > PB ? MLPFIX + 64*1920L : PB);

  long wsf = (long)(ws_size / 4);
  if (wsf < MINREQ) {
    float val = (float)(ws_size >> 20) * 1000.0f + 1.0f;
    fill_kernel<<<dim3((out_size+255)/256), 256, 0, stream>>>(out, out_size, val);
    return;
  }

  long avail = wsf - SMALL - WFIX;
  int G = (int)(avail / PB);
  if (G > NBATCH) G = NBATCH;
  if (G < 1) G = 1;
  long rcl = ((avail - MLPFIX) / 1920L) / 64L * 64L;
  int RC = (int)(rcl > 6336L ? 6336L : rcl);
  if (RC < 64) RC = 64;

  float* ws = (float*)d_ws;
  int*   idx_kept = (int*)ws;
  int*   idx_elim = idx_kept + 6336;
  unsigned short* qkwh   = (unsigned short*)(ws + SMALL);   // [1536][768]
  unsigned short* qkwl   = qkwh + 1179648;                  // [1536][768]
  unsigned short* qkvwvT = qkwl + 1179648;                  // [768][768]
  unsigned short* projwT = qkvwvT + 589824;                 // [768][768]
  float* base  = ws + SMALL + WFIX;
  float* attnc = base;                                      // G*AB
  // q region (G*XROW floats): pre-split q hi/lo, aliased later by x1c fp32
  unsigned short* qh = (unsigned short*)(base + (long)G*AB);
  unsigned short* ql = qh + (long)G*XROW;
  float* x1c = (float*)qh;
  // k region (G*XROW floats): pre-split k hi/lo, aliased later by aoutb bf16
  unsigned short* kh = (unsigned short*)(base + (long)G*AB + (long)G*XROW);
  unsigned short* kl = kh + (long)G*XROW;
  unsigned short* aoutb = kh;
  unsigned short* vt = (unsigned short*)(base + (long)G*AB + 2L*G*XROW);  // G*XROW/2 floats: v^T bf16 [bh][d][tok]
  // h1 region (G*XROW floats): LN1 output pre-split hi/lo
  unsigned short* h1h = (unsigned short*)(base + (long)G*AB + 2L*G*XROW + (long)G*XROW/2);
  unsigned short* h1l = h1h + (long)G*XROW;
  // MLP phase (chunk area reuse):
  unsigned short* fc1wT = (unsigned short*)base;            // [3072][768]
  unsigned short* fc2wT = fc1wT + 2359296;                  // [768][3072]
  unsigned short* h2b   = (unsigned short*)(base + MLPFIX); // RC*768
  unsigned short* gb    = h2b + (long)RC*CD;                // RC*3072

  // Phase 0: weight prep for attention
  tcast3_k<<<dim3(48,24), 256, 0, stream>>>(qkvw, CD, 3*CD, 0, qkwh, qkwl);
  tcast_k <<<dim3(24,24), 256, 0, stream>>>(qkvw, CD, 3*CD, 2*CD, qkvwvT);
  tcast_k <<<dim3(24,24), 256, 0, stream>>>(projw, CD, CD, 0, projwT);

  for (int b0 = 0; b0 < NBATCH; b0 += G) {
    int GL = (NBATCH - b0 < G) ? (NBATCH - b0) : G;
    int MROW = GL*NTOK;
    // LN1 -> h1h/h1l bf16 hi/lo
    ln_kernel<<<dim3(MROW), 256, 0, stream>>>(x + (long)b0*XROW, n1g, n1b, h1h, h1l);
    // qk bf16x3 MFMA: h1 @ qkw^T -> qh/ql (scaled), kh/kl (pre-split scatter)
    {
      Mm3P p{}; p.Ah=h1h; p.Al=h1l; p.Bh=qkwh; p.Bl=qkwl;
      p.qh=qh; p.ql=ql; p.kh=kh; p.kl=kl;
      p.M=MROW; p.N=2*CD; p.K=CD; p.ldc=0; p.az=0; p.bz=0; p.cz=0;
      mgemm3_k<1><<<dim3(12,(MROW+127)/128,1), 256, 0, stream>>>(p);
    }
    // v MFMA (single bf16): h1h @ qkvwvT^T -> vt transposed scatter (vtrans fused)
    {
      MmP p{}; p.A=h1h; p.B=qkvwvT; p.vout=vt;
      p.M=MROW; p.N=CD; p.K=CD; p.ldc=CD;
      mgemm_k<1><<<dim3(6,(MROW+127)/128,1), 256, 0, stream>>>(p);
    }
    // fused S = q @ k^T (bf16x3) + softmax -> attnc fp32
    sqs_k<<<dim3(2, GL*NH), 256, 0, stream>>>(qh, ql, kh, kl, attnc);
    select_kernel<<<dim3(GL), 256, 0, stream>>>(attnc, idx_kept, idx_elim, b0);
    // attn @ v via MFMA (P cast bf16 at stage, B = vt bf16) -> aoutb bf16
    {
      PvP p{}; p.P=attnc; p.Vt=vt; p.C=aoutb;
      pv_k<<<dim3(1,2,GL*NH), 256, 0, stream>>>(p);
    }
    // proj MFMA: x1c = x + aoutb @ projwT^T + proj_b (fp32)
    {
      MmP p{}; p.A=aoutb; p.B=projwT; p.C=x1c;
      p.M=MROW; p.N=CD; p.K=CD; p.ldc=CD;
      p.bias=projb; p.resid=x + (long)b0*XROW;
      mgemm_k<2><<<dim3(6,(MROW+127)/128,1), 256, 0, stream>>>(p);
    }
    // fused threshold + propagation -> x2 (f32) in d_out
    prop_kernel<<<dim3(GL*NH), 256, 0, stream>>>(attnc, x1c, idx_kept, idx_elim, out, b0);
  }

  // ---- MLP weight prep (chunk area now free) ----
  tcast_k<<<dim3(96,24), 256, 0, stream>>>(fc1w, CD, 4*CD, 0, fc1wT);
  tcast_k<<<dim3(24,96), 256, 0, stream>>>(fc2w, 4*CD, CD, 0, fc2wT);

  // ---- MLP, row-chunked; x2 lives in d_out (f32), fc2 overwrites in place ----
  for (int r0 = 0; r0 < NBATCH*KTOK; r0 += RC) {
    int RCL = (NBATCH*KTOK - r0 < RC) ? (NBATCH*KTOK - r0) : RC;
    ln_kernel<<<dim3(RCL), 256, 0, stream>>>(out + (long)r0*CD, n2g, n2b, h2b, nullptr);
    {
      MmP p{}; p.A=h2b; p.B=fc1wT; p.C=gb;
      p.M=RCL; p.N=4*CD; p.K=CD; p.ldc=4*CD; p.bias=fc1b;
      mgemm_k<3><<<dim3(24,(RCL+127)/128,1), 256, 0, stream>>>(p);
    }
    {
      MmP p{}; p.A=gb; p.B=fc2wT; p.C=out + (long)r0*CD;
      p.M=RCL; p.N=CD; p.K=4*CD; p.ldc=CD;
      p.bias=fc2b; p.resid=out + (long)r0*CD;
      mgemm_k<2><<<dim3(6,(RCL+127)/128,1), 256, 0, stream>>>(p);
    }
  }
}

// Round 11
// 709.165 us; speedup vs baseline: 1.2648x; 1.0294x over previous
//
#include <hip/hip_runtime.h>
#include <math.h>

#define NTOK 197
#define CD   768
#define NH   12
#define DH   64
#define NBATCH 64
#define RTOK 98
#define KTOK 99
#define THRN 1941   /* count(w >= thr) >= thr_idx+1 = 1941 */
#define WTOT (KTOK*RTOK)   /* 9702 */
#define SROWS 208

typedef __attribute__((ext_vector_type(8))) short short8;
typedef __attribute__((ext_vector_type(8))) unsigned short u16x8;
typedef __attribute__((ext_vector_type(4))) float floatx4;

__device__ __forceinline__ int clamp196(int v){ return ((unsigned)v > 196u) ? 196 : v; }
__device__ __forceinline__ unsigned short f2b(float f){
  unsigned u = __float_as_uint(f);
  return (unsigned short)((u + 0x7FFFu + ((u>>16)&1u)) >> 16);
}
__device__ __forceinline__ float us2f(unsigned short u){ return __uint_as_float(((unsigned)u)<<16); }
// LDS chunk swizzle for short[row][32] tiles: XOR 16B-chunk index with (row>>1)&3.
__device__ __forceinline__ int swz(int row, int q){ return q ^ (((row>>1)&3)<<3); }

// load up to 8 fp32 (rem valid), cast to bf16 (round-to-nearest)
__device__ __forceinline__ void ldcvt(const float* ap, int rem, u16x8& h){
  float v[8];
  if (rem >= 8) {
    float4 t0 = *(const float4*)ap, t1 = *(const float4*)(ap+4);
    v[0]=t0.x; v[1]=t0.y; v[2]=t0.z; v[3]=t0.w;
    v[4]=t1.x; v[5]=t1.y; v[6]=t1.z; v[7]=t1.w;
  } else {
#pragma unroll
    for (int j=0;j<8;j++) v[j] = (j < rem) ? ap[j] : 0.f;
  }
#pragma unroll
  for (int j=0;j<8;j++) h[j] = f2b(v[j]);
}

// ---------------- diagnostic fill ----------------
__global__ __launch_bounds__(256) void fill_kernel(float* __restrict__ out, int n, float val)
{
  int i = blockIdx.x*256 + threadIdx.x;
  if (i < n) out[i] = val;
}

// ---------------- transpose+cast: dst[n][k] = bf16(src[k][col0+n]) ----------------
__global__ __launch_bounds__(256) void tcast_k(const float* __restrict__ src, int K, int ldn, int col0,
                                               unsigned short* __restrict__ dst)
{
  __shared__ float t[32][33];
  int n0 = blockIdx.x*32, k0 = blockIdx.y*32;
  int lx = threadIdx.x & 31, ly = threadIdx.x >> 5;
#pragma unroll
  for (int i=0;i<4;i++)
    t[ly + i*8][lx] = src[(long)(k0 + ly + i*8)*ldn + col0 + n0 + lx];
  __syncthreads();
#pragma unroll
  for (int i=0;i<4;i++){
    int n = ly + i*8;
    dst[(long)(n0 + n)*K + k0 + lx] = f2b(t[lx][n]);
  }
}

// ---------------- transpose + hi/lo split ----------------
__global__ __launch_bounds__(256) void tcast3_k(const float* __restrict__ src, int K, int ldn, int col0,
                                                unsigned short* __restrict__ dsth,
                                                unsigned short* __restrict__ dstl)
{
  __shared__ float t[32][33];
  int n0 = blockIdx.x*32, k0 = blockIdx.y*32;
  int lx = threadIdx.x & 31, ly = threadIdx.x >> 5;
#pragma unroll
  for (int i=0;i<4;i++)
    t[ly + i*8][lx] = src[(long)(k0 + ly + i*8)*ldn + col0 + n0 + lx];
  __syncthreads();
#pragma unroll
  for (int i=0;i<4;i++){
    int n = ly + i*8;
    float v = t[lx][n];
    unsigned short h = f2b(v);
    dsth[(long)(n0 + n)*K + k0 + lx] = h;
    dstl[(long)(n0 + n)*K + k0 + lx] = f2b(v - us2f(h));
  }
}

// ---------------- LayerNorm (row 768; bf16 hi (+ optional lo) out) ----------------
__global__ __launch_bounds__(256) void ln_kernel(const float* __restrict__ xin,
                                                 const float* __restrict__ gam,
                                                 const float* __restrict__ bet,
                                                 unsigned short* __restrict__ outh,
                                                 unsigned short* __restrict__ outl)
{
  int row = blockIdx.x;
  int tid = threadIdx.x;
  long base = (long)row * CD;
  float v[3];
#pragma unroll
  for (int i=0;i<3;i++) v[i] = xin[base + tid + i*256];
  float s  = v[0]+v[1]+v[2];
  float s2 = v[0]*v[0]+v[1]*v[1]+v[2]*v[2];
#pragma unroll
  for (int off=32; off; off>>=1){ s += __shfl_down(s,off); s2 += __shfl_down(s2,off); }
  __shared__ float ps[4], ps2[4], mb[2];
  if ((tid&63)==0){ ps[tid>>6]=s; ps2[tid>>6]=s2; }
  __syncthreads();
  if (tid==0){
    float S  = ps[0]+ps[1]+ps[2]+ps[3];
    float S2 = ps2[0]+ps2[1]+ps2[2]+ps2[3];
    float m  = S / (float)CD;
    float var = S2 / (float)CD - m*m;
    mb[0]=m; mb[1]=1.0f/sqrtf(var + 1e-5f);
  }
  __syncthreads();
  float m=mb[0], inv=mb[1];
#pragma unroll
  for (int i=0;i<3;i++){
    int c = tid + i*256;
    float r = (v[i]-m)*inv*gam[c] + bet[c];
    unsigned short h = f2b(r);
    outh[base+c] = h;
    if (outl) outl[base+c] = f2b(r - us2f(h));
  }
}

// ---------------- fused S=q@k^T (bf16x3) + row softmax, per z=(b,h) ----------------
__global__ __launch_bounds__(256) void sqs_k(const unsigned short* __restrict__ Qh,
                                             const unsigned short* __restrict__ Ql,
                                             const unsigned short* __restrict__ Kh,
                                             const unsigned short* __restrict__ Kl,
                                             float* __restrict__ S)
{
  __shared__ short Bh_s[SROWS*64], Bl_s[SROWS*64];
  int tid = threadIdx.x;
  int z = blockIdx.y;
  int m0 = blockIdx.x * 128;
  const unsigned short* qhz = Qh + (long)z*NTOK*DH;
  const unsigned short* qlz = Ql + (long)z*NTOK*DH;
  const unsigned short* khz = Kh + (long)z*NTOK*DH;
  const unsigned short* klz = Kl + (long)z*NTOK*DH;
  u16x8 zz = {0,0,0,0,0,0,0,0};
  for (int i = tid; i < SROWS*8; i += 256) {
    int row = i>>3, c = i&7;
    u16x8 vh = zz, vl = zz;
    if (row < NTOK) {
      vh = *(const u16x8*)(khz + (long)row*DH + c*8);
      vl = *(const u16x8*)(klz + (long)row*DH + c*8);
    }
    int off = row*64 + ((c ^ (row&7))<<3);
    *(u16x8*)&Bh_s[off] = vh;
    *(u16x8*)&Bl_s[off] = vl;
  }
  __syncthreads();
  int w = tid>>6, l = tid&63;
  int lr = l&15, hi2 = l>>4, kq = hi2*8;
  int rbase0 = m0 + (w<<5);
  floatx4 acc[2][13];
#pragma unroll
  for (int mt=0;mt<2;mt++)
#pragma unroll
    for (int nt=0;nt<13;nt++) acc[mt][nt] = (floatx4){0.f,0.f,0.f,0.f};
#pragma unroll
  for (int ks=0; ks<2; ks++){
    int k0 = ks*32;
    short8 afh[2], afl[2];
#pragma unroll
    for (int mt=0;mt<2;mt++){
      int rowA = clamp196(rbase0 + mt*16 + lr);
      long qo = (long)rowA*DH + k0 + kq;
      afh[mt] = *(const short8*)(qhz + qo);
      afl[mt] = *(const short8*)(qlz + qo);
    }
#pragma unroll
    for (int nt=0;nt<13;nt++){
      int rowB = nt*16 + lr;
      int cc = (ks<<2) + hi2;
      int off = rowB*64 + ((cc ^ (rowB&7))<<3);
      short8 bfh = *(short8*)&Bh_s[off];
      short8 bfl = *(short8*)&Bl_s[off];
#pragma unroll
      for (int mt=0;mt<2;mt++){
        acc[mt][nt] = __builtin_amdgcn_mfma_f32_16x16x32_bf16(afh[mt], bfh, acc[mt][nt], 0, 0, 0);
        acc[mt][nt] = __builtin_amdgcn_mfma_f32_16x16x32_bf16(afh[mt], bfl, acc[mt][nt], 0, 0, 0);
        acc[mt][nt] = __builtin_amdgcn_mfma_f32_16x16x32_bf16(afl[mt], bfh, acc[mt][nt], 0, 0, 0);
      }
    }
  }
  float* Sz = S + (long)z*NTOK*NTOK;
#pragma unroll
  for (int mt=0;mt<2;mt++){
#pragma unroll
    for (int r=0;r<4;r++){
      int row = rbase0 + mt*16 + hi2*4 + r;
      float ev[13];
      float mx = -3.4e38f;
#pragma unroll
      for (int nt=0;nt<13;nt++){
        int col = nt*16 + lr;
        float v = acc[mt][nt][r];
        if (col >= NTOK) v = -3.4e38f;
        ev[nt] = v;
        mx = fmaxf(mx, v);
      }
#pragma unroll
      for (int mk=1; mk<16; mk<<=1) mx = fmaxf(mx, __shfl_xor(mx, mk));
      float sum = 0.f;
#pragma unroll
      for (int nt=0;nt<13;nt++){
        float e = expf(ev[nt]-mx);
        ev[nt] = e;
        sum += e;
      }
#pragma unroll
      for (int mk=1; mk<16; mk<<=1) sum += __shfl_xor(sum, mk);
      if (row < NTOK){
#pragma unroll
        for (int nt=0;nt<13;nt++){
          int col = nt*16 + lr;
          if (col < NTOK) Sz[(long)row*NTOK + col] = ev[nt]/sum;
        }
      }
    }
  }
}

// ---------------- PV MFMA: C[197,64] = P[197,197] @ V[197,64] per z=(b,h) ----------------
// A = P cast to single bf16 at stage (P in [0,1], rows sum to 1 -> rounding error
// ~2^-9 relative, dominated by aoutb's own bf16 rounding); B = vt bf16 [z][64][197].
struct PvP {
  const float* P;
  const unsigned short* Vt;
  unsigned short* C;
};

__global__ __launch_bounds__(256) void pv_k(PvP p)
{
  __shared__ short Ahs[128*32], Bs[64*32];
  int tid = threadIdx.x;
  int z = blockIdx.z;
  int cb = z / NH, h = z - cb*NH;
  const float* Az = p.P + (long)z*NTOK*NTOK;
  const unsigned short* Bz = p.Vt + (long)z*DH*NTOK;
  int m0 = blockIdx.y*128;
  int w = tid>>6, l = tid&63;
  int wm = (w&1)*64, wn = (w>>1)*32;
  int lr = l&15, kq = (l>>4)*8;
  floatx4 acc[4][2];
#pragma unroll
  for (int i=0;i<4;i++)
#pragma unroll
    for (int j=0;j<2;j++) acc[i][j] = (floatx4){0.f,0.f,0.f,0.f};
  int r0i = tid>>2, q0 = (tid&3)*8;
  int r1i = r0i + 64;
  int w0s = swz(r0i, q0), w1s = swz(r1i, q0);
  for (int k0 = 0; k0 < NTOK; k0 += 32) {
    u16x8 ah0={0,0,0,0,0,0,0,0};
    u16x8 ah1={0,0,0,0,0,0,0,0};
    u16x8 b0 ={0,0,0,0,0,0,0,0};
    int rem = NTOK - k0 - q0;
    { int gm = m0 + r0i;
      if (gm < NTOK && rem > 0) ldcvt(Az + (long)gm*NTOK + k0 + q0, rem, ah0); }
    { int gm = m0 + r1i;
      if (gm < NTOK && rem > 0) ldcvt(Az + (long)gm*NTOK + k0 + q0, rem, ah1); }
    { const unsigned short* bp = Bz + (long)r0i*NTOK + k0 + q0;
      if (rem >= 8) b0 = *(const u16x8*)bp;
      else if (rem > 0) {
#pragma unroll
        for (int j=0;j<8;j++) if (j < rem) b0[j] = bp[j];
      } }
    __syncthreads();
    *(u16x8*)&Ahs[r0i*32 + w0s] = ah0;
    *(u16x8*)&Ahs[r1i*32 + w1s] = ah1;
    *(u16x8*)&Bs [r0i*32 + w0s] = b0;
    __syncthreads();
    short8 afh[4], bfr[2];
#pragma unroll
    for (int mt=0;mt<4;mt++){
      int rr = wm + mt*16 + lr;
      afh[mt] = *(short8*)&Ahs[rr*32 + swz(rr,kq)];
    }
#pragma unroll
    for (int nt=0;nt<2;nt++){
      int rr = wn + nt*16 + lr;
      bfr[nt] = *(short8*)&Bs[rr*32 + swz(rr,kq)];
    }
#pragma unroll
    for (int mt=0;mt<4;mt++)
#pragma unroll
      for (int nt=0;nt<2;nt++)
        acc[mt][nt] = __builtin_amdgcn_mfma_f32_16x16x32_bf16(afh[mt], bfr[nt], acc[mt][nt], 0, 0, 0);
  }
  int rbase = (l>>4)*4;
#pragma unroll
  for (int mt=0;mt<4;mt++){
#pragma unroll
    for (int r=0;r<4;r++){
      int gm = m0 + wm + mt*16 + rbase + r;
      if (gm >= NTOK) continue;
#pragma unroll
      for (int nt=0;nt<2;nt++){
        int gn = wn + nt*16 + lr;   // d in 0..63
        p.C[(long)cb*NTOK*CD + (long)gm*CD + h*DH + gn] = f2b(acc[mt][nt][r]);
      }
    }
  }
}

// ---------------- bf16 MFMA GEMM (reg-staged, BK=32) ----------------
// EPI 1: v -> vt bf16 transposed scatter [bh][d][tok] (fuses the old vtrans pass)
struct MmP {
  const unsigned short* A;
  const unsigned short* B;
  void* C;
  const float* bias;
  const float* resid;
  unsigned short* vout;
  int M, N, K, ldc;
};

template<int EPI>
__global__ __launch_bounds__(256) void mgemm_k(MmP p)
{
  __shared__ short As[128*32];
  __shared__ short Bs[128*32];
  int tid = threadIdx.x;
  int m0 = blockIdx.y*128, n0 = blockIdx.x*128;
  int w = tid>>6, l = tid&63;
  int wm = (w&1)*64, wn = (w>>1)*64;
  int lr = l&15, kq = (l>>4)*8;
  floatx4 acc[4][4];
#pragma unroll
  for (int i=0;i<4;i++)
#pragma unroll
    for (int j=0;j<4;j++) acc[i][j] = (floatx4){0.f,0.f,0.f,0.f};
  int r0i = tid>>2, q0 = (tid&3)*8;
  int r1i = r0i + 64;
  int w0s = swz(r0i, q0), w1s = swz(r1i, q0);
  for (int k0 = 0; k0 < p.K; k0 += 32) {
    u16x8 a0 = {0,0,0,0,0,0,0,0}, a1 = {0,0,0,0,0,0,0,0};
    { int gm = m0 + r0i;
      if (gm < p.M) a0 = *(const u16x8*)(p.A + (long)gm*p.K + k0 + q0); }
    { int gm = m0 + r1i;
      if (gm < p.M) a1 = *(const u16x8*)(p.A + (long)gm*p.K + k0 + q0); }
    u16x8 b0 = *(const u16x8*)(p.B + (long)(n0 + r0i)*p.K + k0 + q0);
    u16x8 b1 = *(const u16x8*)(p.B + (long)(n0 + r1i)*p.K + k0 + q0);
    __syncthreads();
    *(u16x8*)&As[r0i*32 + w0s] = a0;
    *(u16x8*)&As[r1i*32 + w1s] = a1;
    *(u16x8*)&Bs[r0i*32 + w0s] = b0;
    *(u16x8*)&Bs[r1i*32 + w1s] = b1;
    __syncthreads();
    short8 af[4], bfr[4];
#pragma unroll
    for (int mt=0;mt<4;mt++){ int rr = wm + mt*16 + lr; af[mt]  = *(short8*)&As[rr*32 + swz(rr,kq)]; }
#pragma unroll
    for (int nt=0;nt<4;nt++){ int rr = wn + nt*16 + lr; bfr[nt] = *(short8*)&Bs[rr*32 + swz(rr,kq)]; }
#pragma unroll
    for (int mt=0;mt<4;mt++)
#pragma unroll
      for (int nt=0;nt<4;nt++)
        acc[mt][nt] = __builtin_amdgcn_mfma_f32_16x16x32_bf16(af[mt], bfr[nt], acc[mt][nt], 0, 0, 0);
  }
  int rbase = (l>>4)*4;   // C/D: col=lane&15, row=(lane>>4)*4+reg  [m89-verified]
#pragma unroll
  for (int mt=0;mt<4;mt++){
#pragma unroll
    for (int r=0;r<4;r++){
      int gm = m0 + wm + mt*16 + rbase + r;
      if (gm >= p.M) continue;
#pragma unroll
      for (int nt=0;nt<4;nt++){
        int gn = n0 + wn + nt*16 + lr;
        float val = acc[mt][nt][r];
        if (EPI == 1) {   // v -> vt bf16 transposed scatter [bh][d][tok]
          int cb = gm / NTOK, tok = gm - cb*NTOK;
          int h = gn >> 6, d = gn & 63;
          p.vout[(((long)cb*NH + h)*DH + d)*NTOK + tok] = f2b(val);
        } else if (EPI == 2) {
          ((float*)p.C)[(long)gm*p.ldc + gn] = val + p.bias[gn] + p.resid[(long)gm*p.ldc + gn];
        } else {
          float u = val + p.bias[gn];
          ((unsigned short*)p.C)[(long)gm*p.ldc + gn] = f2b(0.5f*u*(1.0f + erff(u*0.70710678118654752f)));
        }
      }
    }
  }
}

// ---------------- bf16x3 MFMA GEMM (reg-staged, BK=32) ----------------
struct Mm3P {
  const unsigned short *Ah, *Al, *Bh, *Bl;
  float* C;
  unsigned short *qh, *ql, *kh, *kl;
  long az, bz, cz;
  int M, N, K, ldc;
};

template<int EPI>
__global__ __launch_bounds__(256) void mgemm3_k(Mm3P p)
{
  __shared__ short Ahs[128*32], Als[128*32], Bhs[128*32], Bls[128*32];
  int tid = threadIdx.x;
  int z = blockIdx.z;
  const unsigned short* Azh = p.Ah + (long)z*p.az;
  const unsigned short* Azl = p.Al + (long)z*p.az;
  const unsigned short* Bzh = p.Bh + (long)z*p.bz;
  const unsigned short* Bzl = p.Bl + (long)z*p.bz;
  int m0 = blockIdx.y*128, n0 = blockIdx.x*128;
  int w = tid>>6, l = tid&63;
  int wm = (w&1)*64, wn = (w>>1)*64;
  int lr = l&15, kq = (l>>4)*8;
  floatx4 acc[4][4];
#pragma unroll
  for (int i=0;i<4;i++)
#pragma unroll
    for (int j=0;j<4;j++) acc[i][j] = (floatx4){0.f,0.f,0.f,0.f};
  int r0i = tid>>2, q0 = (tid&3)*8;
  int r1i = r0i + 64;
  int w0s = swz(r0i, q0), w1s = swz(r1i, q0);
  for (int k0 = 0; k0 < p.K; k0 += 32) {
    u16x8 ah0={0,0,0,0,0,0,0,0}, al0={0,0,0,0,0,0,0,0};
    u16x8 ah1={0,0,0,0,0,0,0,0}, al1={0,0,0,0,0,0,0,0};
    u16x8 bh0={0,0,0,0,0,0,0,0}, bl0={0,0,0,0,0,0,0,0};
    u16x8 bh1={0,0,0,0,0,0,0,0}, bl1={0,0,0,0,0,0,0,0};
    { int gm = m0 + r0i;
      if (gm < p.M) {
        long o = (long)gm*p.K + k0 + q0;
        ah0 = *(const u16x8*)(Azh + o);
        al0 = *(const u16x8*)(Azl + o);
      } }
    { int gm = m0 + r1i;
      if (gm < p.M) {
        long o = (long)gm*p.K + k0 + q0;
        ah1 = *(const u16x8*)(Azh + o);
        al1 = *(const u16x8*)(Azl + o);
      } }
    { int gn = n0 + r0i;
      if (gn < p.N) {
        long o = (long)gn*p.K + k0 + q0;
        bh0 = *(const u16x8*)(Bzh + o);
        bl0 = *(const u16x8*)(Bzl + o);
      } }
    { int gn = n0 + r1i;
      if (gn < p.N) {
        long o = (long)gn*p.K + k0 + q0;
        bh1 = *(const u16x8*)(Bzh + o);
        bl1 = *(const u16x8*)(Bzl + o);
      } }
    __syncthreads();
    *(u16x8*)&Ahs[r0i*32 + w0s] = ah0;
    *(u16x8*)&Ahs[r1i*32 + w1s] = ah1;
    *(u16x8*)&Als[r0i*32 + w0s] = al0;
    *(u16x8*)&Als[r1i*32 + w1s] = al1;
    *(u16x8*)&Bhs[r0i*32 + w0s] = bh0;
    *(u16x8*)&Bhs[r1i*32 + w1s] = bh1;
    *(u16x8*)&Bls[r0i*32 + w0s] = bl0;
    *(u16x8*)&Bls[r1i*32 + w1s] = bl1;
    __syncthreads();
    short8 afh[4], afl[4], bfh[4], bfl[4];
#pragma unroll
    for (int mt=0;mt<4;mt++){
      int rr = wm + mt*16 + lr; int rs = rr*32 + swz(rr,kq);
      afh[mt] = *(short8*)&Ahs[rs];
      afl[mt] = *(short8*)&Als[rs];
    }
#pragma unroll
    for (int nt=0;nt<4;nt++){
      int rr = wn + nt*16 + lr; int rs = rr*32 + swz(rr,kq);
      bfh[nt] = *(short8*)&Bhs[rs];
      bfl[nt] = *(short8*)&Bls[rs];
    }
#pragma unroll
    for (int mt=0;mt<4;mt++)
#pragma unroll
      for (int nt=0;nt<4;nt++){
        acc[mt][nt] = __builtin_amdgcn_mfma_f32_16x16x32_bf16(afh[mt], bfh[nt], acc[mt][nt], 0, 0, 0);
        acc[mt][nt] = __builtin_amdgcn_mfma_f32_16x16x32_bf16(afh[mt], bfl[nt], acc[mt][nt], 0, 0, 0);
        acc[mt][nt] = __builtin_amdgcn_mfma_f32_16x16x32_bf16(afl[mt], bfh[nt], acc[mt][nt], 0, 0, 0);
      }
  }
  int rbase = (l>>4)*4;
#pragma unroll
  for (int mt=0;mt<4;mt++){
#pragma unroll
    for (int r=0;r<4;r++){
      int gm = m0 + wm + mt*16 + rbase + r;
      if (gm >= p.M) continue;
#pragma unroll
      for (int nt=0;nt<4;nt++){
        int gn = n0 + wn + nt*16 + lr;
        if (gn >= p.N) continue;
        float val = acc[mt][nt][r];
        if (EPI == 0) {
          p.C[(long)z*p.cz + (long)gm*p.ldc + gn] = val;
        } else {   // qk scatter, pre-split
          int which = (gn >= CD) ? 1 : 0;
          int rc = gn - which*CD;
          int hd = rc >> 6, dd = rc & 63;
          int cb = gm / NTOK, tok = gm - cb*NTOK;
          long off = (((long)cb*NH + hd)*NTOK + tok)*DH + dd;
          float v = which ? val : val*0.125f;
          unsigned short h = f2b(v);
          unsigned short lo16 = f2b(v - us2f(h));
          if (which) { p.kh[off] = h; p.kl[off] = lo16; }
          else       { p.qh[off] = h; p.ql[off] = lo16; }
        }
      }
    }
  }
}

// ---------------- token selection ----------------
__global__ __launch_bounds__(256) void select_kernel(const float* __restrict__ attn,
                                                     int* __restrict__ idx_kept,
                                                     int* __restrict__ idx_elim, int b0)
{
  int cb = blockIdx.x, tid = threadIdx.x;
  int b = b0 + cb;
  __shared__ float diag[NTOK-1];
  __shared__ int kept[NTOK];
  if (tid < NTOK-1) {
    int t = tid + 1;
    float s = 0.f;
#pragma unroll
    for (int h=0; h<NH; h++)
      s += attn[(((long)cb*NH + h)*NTOK + t)*NTOK + t];
    diag[tid] = s / 12.0f;
  }
  if (tid < KTOK) idx_kept[b*KTOK + tid] = 0;
  if (tid < RTOK) idx_elim[b*RTOK + tid] = 1;
  __syncthreads();
  if (tid < NTOK-1) {
    float dv = diag[tid];
    int r = 0;
    for (int m=0; m<NTOK-1; m++){
      float dm = diag[m];
      r += ((dm > dv) || (dm == dv && m < tid)) ? 1 : 0;
    }
    kept[tid+1] = (r < (NTOK-1-RTOK)) ? 1 : 0;
  }
  __syncthreads();
  if (tid < NTOK-1) {
    int t = tid + 1;
    if (kept[t]) {
      int pos = 1;
      for (int s2=1; s2<t; s2++) pos += kept[s2];
      if (pos >= 1 && pos < KTOK) idx_kept[b*KTOK + pos] = t;
    } else {
      int pos = 0;
      for (int s2=1; s2<t; s2++) pos += 1 - kept[s2];
      if (pos >= 0 && pos < RTOK) idx_elim[b*RTOK + pos] = t;
    }
  }
  if (tid == 0) idx_kept[b*KTOK] = 0;
}

// ---------------- fused threshold + propagation (radix-select + MFMA) ----------------
#define PNEL 38   /* ceil(9702/256) */
__global__ __launch_bounds__(256) void prop_kernel(const float* __restrict__ attn,
                                                   const float* __restrict__ x1c,
                                                   const int* __restrict__ idx_kept,
                                                   const int* __restrict__ idx_elim,
                                                   float* __restrict__ x2, int b0)
{
  int z = blockIdx.x;
  int cb = z / NH, h = z - cb*NH;
  int b = b0 + cb;
  int tid = threadIdx.x;
  int wid = tid >> 6, l = tid & 63;
  int lr = l & 15, hi2 = l >> 4;
  __shared__ short WhL[112*128];
  __shared__ short XtL[64*128];
  __shared__ unsigned hist[64];
  __shared__ int kidx[KTOK], eidx[RTOK];
  if (tid < KTOK) kidx[tid] = clamp196(idx_kept[b*KTOK + tid]);
  if (tid < RTOK) eidx[tid] = clamp196(idx_elim[b*RTOK + tid]);
  u16x8 zz = {0,0,0,0,0,0,0,0};
#pragma unroll
  for (int i=0;i<7;i++) *(u16x8*)&WhL[tid*8 + i*2048] = zz;
#pragma unroll
  for (int i=0;i<4;i++) *(u16x8*)&XtL[tid*8 + i*2048] = zz;
  __syncthreads();
  for (int i = tid; i < RTOK*DH; i += 256){
    int e = i >> 6, d = i & 63;
    float v = x1c[((long)cb*NTOK + eidx[e])*CD + h*DH + d];
    XtL[d*128 + (((e>>3) ^ (d&7))<<3) + (e&7)] = (short)f2b(v);
  }
  const float* ab = attn + (long)z*NTOK*NTOK;
  unsigned wb[PNEL];
#pragma unroll
  for (int j=0;j<PNEL;j++){
    int i = tid + (j<<8);
    if (i < WTOT){
      int k = i / RTOK, e = i - k*RTOK;
      wb[j] = __float_as_uint(ab[kidx[k]*NTOK + eidx[e]]);
    } else wb[j] = 0u;
  }
  unsigned P = 0; int rrank = THRN;
  for (int pass=0; pass<5; ++pass){
    int sh = 24 - 6*pass;
    if (tid < 64) hist[tid] = 0u;
    __syncthreads();
#pragma unroll
    for (int j=0;j<PNEL;j++){
      int i = tid + (j<<8);
      unsigned v = wb[j];
      bool m = (i < WTOT) && ((pass == 0) || ((v >> (sh+6)) == P));
      if (m) atomicAdd(&hist[(v>>sh)&63u], 1u);
    }
    __syncthreads();
    unsigned cum = 0; int bsel = 0; unsigned above = 0;
    for (int bb=63; bb>=0; --bb){
      unsigned hv = hist[bb];
      if (cum + hv >= (unsigned)rrank){ bsel = bb; above = cum; break; }
      cum += hv;
    }
    P = (P<<6) | (unsigned)bsel;
    rrank -= (int)above;
    __syncthreads();
  }
  unsigned thrbits = P;
#pragma unroll
  for (int j=0;j<PNEL;j++){
    int i = tid + (j<<8);
    if (i < WTOT){
      int k = i / RTOK, e = i - k*RTOK;
      unsigned v = (wb[j] >= thrbits) ? wb[j] : 0u;
      WhL[k*128 + (((e>>3) ^ (k&7))<<3) + (e&7)] = (short)f2b(__uint_as_float(v));
    }
  }
  __syncthreads();
  floatx4 acc[7];
#pragma unroll
  for (int mt=0;mt<7;mt++) acc[mt] = (floatx4){0.f,0.f,0.f,0.f};
  short8 bfr[4];
#pragma unroll
  for (int ks=0;ks<4;ks++){
    int c = ks*4 + hi2;
    int rd = wid*16 + lr;
    bfr[ks] = *(short8*)&XtL[rd*128 + ((c ^ (lr&7))<<3)];
  }
#pragma unroll
  for (int mt=0;mt<7;mt++){
#pragma unroll
    for (int ks=0;ks<4;ks++){
      int c = ks*4 + hi2;
      int rw = mt*16 + lr;
      short8 af = *(short8*)&WhL[rw*128 + ((c ^ (lr&7))<<3)];
      acc[mt] = __builtin_amdgcn_mfma_f32_16x16x32_bf16(af, bfr[ks], acc[mt], 0, 0, 0);
    }
  }
#pragma unroll
  for (int mt=0;mt<7;mt++){
#pragma unroll
    for (int r=0;r<4;r++){
      int kt = mt*16 + hi2*4 + r;
      if (kt >= KTOK) continue;
      int d = wid*16 + lr;
      float xk = x1c[((long)cb*NTOK + kidx[kt])*CD + h*DH + d];
      x2[((long)b*KTOK + kt)*CD + h*DH + d] = xk + 0.1f*acc[mt][r];
    }
  }
}

extern "C" void kernel_launch(void* const* d_in, const int* in_sizes, int n_in,
                              void* d_out, int out_size, void* d_ws, size_t ws_size,
                              hipStream_t stream)
{
  const float* x     = (const float*)d_in[0];
  const float* n1g   = (const float*)d_in[1];
  const float* n1b   = (const float*)d_in[2];
  const float* qkvw  = (const float*)d_in[3];
  const float* projw = (const float*)d_in[4];
  const float* projb = (const float*)d_in[5];
  const float* n2g   = (const float*)d_in[6];
  const float* n2b   = (const float*)d_in[7];
  const float* fc1w  = (const float*)d_in[8];
  const float* fc1b  = (const float*)d_in[9];
  const float* fc2w  = (const float*)d_in[10];
  const float* fc2b  = (const float*)d_in[11];
  float* out = (float*)d_out;

  const long XROW = (long)NTOK*CD;          // 151296
  const long AH   = (long)NTOK*NTOK;        // 38809
  const long AB   = (long)NH*AH;            // 465708
  const long SMALL = 6336L + 6272L;         // 12608 floats
  const long WFIX  = 1769472L;              // qkwh+qkwl+qkvwvT+projwT (floats)
  const long PB = AB + 3*XROW + XROW/2;     // floats per batch
  const long MLPFIX = 2359296L;             // fc1wT+fc2wT (floats), in chunk area
  const long MINREQ = SMALL + WFIX + (MLPFIX + 64*1920L > PB ? MLPFIX + 64*1920L : PB);

  long wsf = (long)(ws_size / 4);
  if (wsf < MINREQ) {
    float val = (float)(ws_size >> 20) * 1000.0f + 1.0f;
    fill_kernel<<<dim3((out_size+255)/256), 256, 0, stream>>>(out, out_size, val);
    return;
  }

  long avail = wsf - SMALL - WFIX;
  int G = (int)(avail / PB);
  if (G > NBATCH) G = NBATCH;
  if (G < 1) G = 1;
  long rcl = ((avail - MLPFIX) / 1920L) / 64L * 64L;
  int RC = (int)(rcl > 6336L ? 6336L : rcl);
  if (RC < 64) RC = 64;

  float* ws = (float*)d_ws;
  int*   idx_kept = (int*)ws;
  int*   idx_elim = idx_kept + 6336;
  unsigned short* qkwh   = (unsigned short*)(ws + SMALL);   // [1536][768]
  unsigned short* qkwl   = qkwh + 1179648;                  // [1536][768]
  unsigned short* qkvwvT = qkwl + 1179648;                  // [768][768]
  unsigned short* projwT = qkvwvT + 589824;                 // [768][768]
  float* base  = ws + SMALL + WFIX;
  float* attnc = base;                                      // G*AB
  // q region (G*XROW floats): pre-split q hi/lo, aliased later by x1c fp32
  unsigned short* qh = (unsigned short*)(base + (long)G*AB);
  unsigned short* ql = qh + (long)G*XROW;
  float* x1c = (float*)qh;
  // k region (G*XROW floats): pre-split k hi/lo, aliased later by aoutb bf16
  unsigned short* kh = (unsigned short*)(base + (long)G*AB + (long)G*XROW);
  unsigned short* kl = kh + (long)G*XROW;
  unsigned short* aoutb = kh;
  unsigned short* vt = (unsigned short*)(base + (long)G*AB + 2L*G*XROW);  // G*XROW/2 floats: v^T bf16 [bh][d][tok]
  // h1 region (G*XROW floats): LN1 output pre-split hi/lo
  unsigned short* h1h = (unsigned short*)(base + (long)G*AB + 2L*G*XROW + (long)G*XROW/2);
  unsigned short* h1l = h1h + (long)G*XROW;
  // MLP phase (chunk area reuse):
  unsigned short* fc1wT = (unsigned short*)base;            // [3072][768]
  unsigned short* fc2wT = fc1wT + 2359296;                  // [768][3072]
  unsigned short* h2b   = (unsigned short*)(base + MLPFIX); // RC*768
  unsigned short* gb    = h2b + (long)RC*CD;                // RC*3072

  // Phase 0: weight prep for attention
  tcast3_k<<<dim3(48,24), 256, 0, stream>>>(qkvw, CD, 3*CD, 0, qkwh, qkwl);
  tcast_k <<<dim3(24,24), 256, 0, stream>>>(qkvw, CD, 3*CD, 2*CD, qkvwvT);
  tcast_k <<<dim3(24,24), 256, 0, stream>>>(projw, CD, CD, 0, projwT);

  for (int b0 = 0; b0 < NBATCH; b0 += G) {
    int GL = (NBATCH - b0 < G) ? (NBATCH - b0) : G;
    int MROW = GL*NTOK;
    // LN1 -> h1h/h1l bf16 hi/lo
    ln_kernel<<<dim3(MROW), 256, 0, stream>>>(x + (long)b0*XROW, n1g, n1b, h1h, h1l);
    // qk bf16x3 MFMA: h1 @ qkw^T -> qh/ql (scaled), kh/kl (pre-split scatter)
    {
      Mm3P p{}; p.Ah=h1h; p.Al=h1l; p.Bh=qkwh; p.Bl=qkwl;
      p.qh=qh; p.ql=ql; p.kh=kh; p.kl=kl;
      p.M=MROW; p.N=2*CD; p.K=CD; p.ldc=0; p.az=0; p.bz=0; p.cz=0;
      mgemm3_k<1><<<dim3(12,(MROW+127)/128,1), 256, 0, stream>>>(p);
    }
    // v MFMA (single bf16): h1h @ qkvwvT^T -> vt transposed scatter (vtrans fused)
    {
      MmP p{}; p.A=h1h; p.B=qkvwvT; p.vout=vt;
      p.M=MROW; p.N=CD; p.K=CD; p.ldc=CD;
      mgemm_k<1><<<dim3(6,(MROW+127)/128,1), 256, 0, stream>>>(p);
    }
    // fused S = q @ k^T (bf16x3) + softmax -> attnc fp32
    sqs_k<<<dim3(2, GL*NH), 256, 0, stream>>>(qh, ql, kh, kl, attnc);
    select_kernel<<<dim3(GL), 256, 0, stream>>>(attnc, idx_kept, idx_elim, b0);
    // attn @ v via MFMA (P cast bf16 at stage, B = vt bf16) -> aoutb bf16
    {
      PvP p{}; p.P=attnc; p.Vt=vt; p.C=aoutb;
      pv_k<<<dim3(1,2,GL*NH), 256, 0, stream>>>(p);
    }
    // proj MFMA: x1c = x + aoutb @ projwT^T + proj_b (fp32)
    {
      MmP p{}; p.A=aoutb; p.B=projwT; p.C=x1c;
      p.M=MROW; p.N=CD; p.K=CD; p.ldc=CD;
      p.bias=projb; p.resid=x + (long)b0*XROW;
      mgemm_k<2><<<dim3(6,(MROW+127)/128,1), 256, 0, stream>>>(p);
    }
    // fused threshold + propagation -> x2 (f32) in d_out
    prop_kernel<<<dim3(GL*NH), 256, 0, stream>>>(attnc, x1c, idx_kept, idx_elim, out, b0);
  }

  // ---- MLP weight prep (chunk area now free) ----
  tcast_k<<<dim3(96,24), 256, 0, stream>>>(fc1w, CD, 4*CD, 0, fc1wT);
  tcast_k<<<dim3(24,96), 256, 0, stream>>>(fc2w, 4*CD, CD, 0, fc2wT);

  // ---- MLP, row-chunked; x2 lives in d_out (f32), fc2 overwrites in place ----
  for (int r0 = 0; r0 < NBATCH*KTOK; r0 += RC) {
    int RCL = (NBATCH*KTOK - r0 < RC) ? (NBATCH*KTOK - r0) : RC;
    ln_kernel<<<dim3(RCL), 256, 0, stream>>>(out + (long)r0*CD, n2g, n2b, h2b, nullptr);
    {
      MmP p{}; p.A=h2b; p.B=fc1wT; p.C=gb;
      p.M=RCL; p.N=4*CD; p.K=CD; p.ldc=4*CD; p.bias=fc1b;
      mgemm_k<3><<<dim3(24,(RCL+127)/128,1), 256, 0, stream>>>(p);
    }
    {
      MmP p{}; p.A=gb; p.B=fc2wT; p.C=out + (long)r0*CD;
      p.M=RCL; p.N=CD; p.K=4*CD; p.ldc=CD;
      p.bias=fc2b; p.resid=out + (long)r0*CD;
      mgemm_k<2><<<dim3(6,(RCL+127)/128,1), 256, 0, stream>>>(p);
    }
  }
}